// Round 8
// baseline (190.692 us; speedup 1.0000x reference)
//
#include <hip/hip_runtime.h>
#include <hip/hip_fp16.h>
#include <math.h>

// N = 160000 = 256 * 625; four-step FFT decomposition.
// R23 = R22 with i2 instrumented: in-kernel REPEAT x3 (reps 0-1 compute into
// LDS only; rep 2 computes AND does the atomicAdd pass -> E accumulated once,
// bit-identical result). Measurement round: total = base + 2*t_i2, and
// rocprof top-5 shows i2 at 3*t_i2. All other kernels unchanged from R22.
// f1: pack w+i*o (float4), 2 waves per 625-column, chained epilogue; zeroes E.
// fi: fused f2+i1, 16 rows / 1024 thr / 4 bands per block (grid 640).
// i2: one wave per 2 columns (AA/AB interleaved chains), fused energy pass.
constexpr int L      = 160000;
constexpr int BATCH  = 8;
constexpr int NB     = 8;
constexpr int NHOPS  = 156;
constexpr int NCHUNK = 155;
constexpr int RS     = 289;   // swizzled row stride
constexpr float TWO_PI = 6.28318530717958647692f;
constexpr float INVL = 1.0f / (float)L;

__device__ __forceinline__ float2 cmulf(float2 a, float2 b) {
  return make_float2(a.x * b.x - a.y * b.y, a.x * b.y + a.y * b.x);
}

__device__ __forceinline__ float2 cisf(float a) {
  float s, c;
  __sincosf(a, &s, &c);
  return make_float2(c, s);
}

__device__ __forceinline__ float2 conjf(float2 a) { return make_float2(a.x, -a.y); }

__device__ __forceinline__ int pad8(int i) { return i + (i >> 3); }

template <int SIGN>
__device__ __forceinline__ void bf4s(float2* v) {
  float2 t0 = make_float2(v[0].x + v[2].x, v[0].y + v[2].y);
  float2 t1 = make_float2(v[0].x - v[2].x, v[0].y - v[2].y);
  float2 t2 = make_float2(v[1].x + v[3].x, v[1].y + v[3].y);
  float2 t3 = make_float2(v[1].x - v[3].x, v[1].y - v[3].y);
  v[0] = make_float2(t0.x + t2.x, t0.y + t2.y);
  v[2] = make_float2(t0.x - t2.x, t0.y - t2.y);
  if constexpr (SIGN < 0) {
    v[1] = make_float2(t1.x + t3.y, t1.y - t3.x);
    v[3] = make_float2(t1.x - t3.y, t1.y + t3.x);
  } else {
    v[1] = make_float2(t1.x - t3.y, t1.y + t3.x);
    v[3] = make_float2(t1.x + t3.y, t1.y - t3.x);
  }
}

template <int SIGN>
__device__ __forceinline__ void bf5s(float2* v) {
  const float c1 = 0.30901699437494745f, s1 = 0.9510565162951535f;
  const float c2 = -0.8090169943749475f, s2 = 0.5877852522924731f;
  float2 t1 = make_float2(v[1].x + v[4].x, v[1].y + v[4].y);
  float2 t3 = make_float2(v[1].x - v[4].x, v[1].y - v[4].y);
  float2 t2 = make_float2(v[2].x + v[3].x, v[2].y + v[3].y);
  float2 t4 = make_float2(v[2].x - v[3].x, v[2].y - v[3].y);
  float2 a = make_float2(v[0].x + c1 * t1.x + c2 * t2.x, v[0].y + c1 * t1.y + c2 * t2.y);
  float2 b = make_float2(s1 * t3.x + s2 * t4.x, s1 * t3.y + s2 * t4.y);
  float2 c = make_float2(v[0].x + c2 * t1.x + c1 * t2.x, v[0].y + c2 * t1.y + c1 * t2.y);
  float2 d = make_float2(s2 * t3.x - s1 * t4.x, s2 * t3.y - s1 * t4.y);
  v[0] = make_float2(v[0].x + t1.x + t2.x, v[0].y + t1.y + t2.y);
  if constexpr (SIGN < 0) {
    v[1] = make_float2(a.x + b.y, a.y - b.x);
    v[4] = make_float2(a.x - b.y, a.y + b.x);
    v[2] = make_float2(c.x + d.y, c.y - d.x);
    v[3] = make_float2(c.x - d.y, c.y + d.x);
  } else {
    v[1] = make_float2(a.x - b.y, a.y + b.x);
    v[4] = make_float2(a.x + b.y, a.y - b.x);
    v[2] = make_float2(c.x - d.y, c.y + d.x);
    v[3] = make_float2(c.x + d.y, c.y - d.x);
  }
}

template <int R>
__device__ __forceinline__ void twchain(float2* v, float2 t1) {
  float2 t = t1;
  v[1] = cmulf(v[1], t);
#pragma unroll
  for (int r = 2; r < R; ++r) { t = cmulf(t, t1); v[r] = cmulf(v[r], t); }
}

__device__ __forceinline__ int rev3_5(int q) {
  int q5 = q / 5, q25 = q / 25;
  int d0 = q - 5 * q5, d1 = q5 - 5 * q25;
  return 25 * d0 + 5 * d1 + q25;
}

__device__ __forceinline__ int rev3_4(int q) {
  return ((q & 3) << 4) | (q & 12) | (q >> 4);
}

// ---------- single-butterfly DIF-625 stage (128 lanes/column, f1) ----------
template <int SUB, int SIGN>
__device__ __forceinline__ void dif5_stage_1b(float2* a, int idx) {
  int j = idx % SUB;
  int b = (idx / SUB) * (5 * SUB) + j;
  float2 u[5];
#pragma unroll
  for (int r = 0; r < 5; ++r) u[r] = a[b + SUB * r];
  bf5s<SIGN>(u);
  twchain<5>(u, cisf((float)SIGN * (TWO_PI / (float)(5 * SUB)) * (float)j));
#pragma unroll
  for (int r = 0; r < 5; ++r) a[b + SUB * r] = u[r];
}

// ---------- dual-butterfly DIF-625 stage, precomputed twiddles (i2) ----------
template <int SUB>
__device__ __forceinline__ void dif5_ip_stage_t(float2* a, int ln, float2 t1a, float2 t1b) {
  int i1 = ln, i2 = ln + 64;
  bool g2 = (i2 < 125);
  int j1 = i1 % SUB, j2 = i2 % SUB;
  int b1 = (i1 / SUB) * (5 * SUB) + j1;
  int b2 = (i2 / SUB) * (5 * SUB) + j2;
  float2 u[5], v[5];
#pragma unroll
  for (int r = 0; r < 5; ++r) u[r] = a[b1 + SUB * r];
  if (g2) {
#pragma unroll
    for (int r = 0; r < 5; ++r) v[r] = a[b2 + SUB * r];
  }
  bf5s<1>(u);
  twchain<5>(u, t1a);
  if (g2) {
    bf5s<1>(v);
    twchain<5>(v, t1b);
  }
#pragma unroll
  for (int r = 0; r < 5; ++r) a[b1 + SUB * r] = u[r];
  if (g2) {
#pragma unroll
    for (int r = 0; r < 5; ++r) a[b2 + SUB * r] = v[r];
  }
}

// ---------- in-place DIF-256, pad8-swizzled, hoisted twiddles ----------
template <int SIGN>
__device__ __forceinline__ void dif256sw_tw(float2* a, int ln,
                                            float2 tw1, float2 tw2, float2 tw3) {
  {
    int b = pad8(ln);            // + 72*r exact
    float2 u[4];
#pragma unroll
    for (int r = 0; r < 4; ++r) u[r] = a[b + 72 * r];
    bf4s<SIGN>(u);
    twchain<4>(u, tw1);
#pragma unroll
    for (int r = 0; r < 4; ++r) a[b + 72 * r] = u[r];
  }
  {
    int j = ln & 15, b = pad8(64 * (ln >> 4) + j);   // + 18*r exact
    float2 u[4];
#pragma unroll
    for (int r = 0; r < 4; ++r) u[r] = a[b + 18 * r];
    bf4s<SIGN>(u);
    twchain<4>(u, tw2);
#pragma unroll
    for (int r = 0; r < 4; ++r) a[b + 18 * r] = u[r];
  }
  {
    int j = ln & 3, jb = 16 * (ln >> 2) + j;
    float2 u[4];
#pragma unroll
    for (int r = 0; r < 4; ++r) u[r] = a[pad8(jb + 4 * r)];
    bf4s<SIGN>(u);
    twchain<4>(u, tw3);
#pragma unroll
    for (int r = 0; r < 4; ++r) a[pad8(jb + 4 * r)] = u[r];
  }
  {
    float2 u[4];
#pragma unroll
    for (int r = 0; r < 4; ++r) u[r] = a[pad8(4 * ln + r)];
    bf4s<SIGN>(u);
    int rv = rev3_4(ln);
#pragma unroll
    for (int r = 0; r < 4; ++r) a[pad8(64 * r + rv)] = u[r];
  }
}

// ---------- F1: float4 pack, 2 waves per 625-column, chained epilogue; zero E ----------
__global__ __launch_bounds__(512) void f1_kernel(const float* __restrict__ win,
                                                 const float* __restrict__ oin,
                                                 float2* __restrict__ G,
                                                 float* __restrict__ E) {
  __shared__ float2 A[4 * 625];    // 20 KB
  int blk = blockIdx.x;            // grid = BATCH * 64 = 512
  int tid = threadIdx.x;
  int gid = blk * 512 + tid;
  if (gid < 2 * BATCH * NB * NHOPS) E[gid] = 0.0f;   // replaces memset launch
  int sig = blk >> 6, g = blk & 63;
  int n1base = g * 4;
  const float4* wp4 = (const float4*)(win + (size_t)sig * L);
  const float4* op4 = (const float4*)(oin + (size_t)sig * L);
  for (int r = tid; r < 625; r += 512) {
    float4 wv = wp4[r * 64 + g];
    float4 ov = op4[r * 64 + g];
    A[0 * 625 + r] = make_float2(wv.x, ov.x);
    A[1 * 625 + r] = make_float2(wv.y, ov.y);
    A[2 * 625 + r] = make_float2(wv.z, ov.z);
    A[3 * 625 + r] = make_float2(wv.w, ov.w);
  }
  __syncthreads();
  // 2 waves per column: 128 lanes, 1 butterfly each (125 active)
  int col = tid >> 7, idx = tid & 127;
  float2* a = A + col * 625;
  bool act = (idx < 125);
  if (act) dif5_stage_1b<125, -1>(a, idx);
  __syncthreads();
  if (act) dif5_stage_1b<25, -1>(a, idx);
  __syncthreads();
  if (act) dif5_stage_1b<5, -1>(a, idx);
  __syncthreads();
  if (act) {
    float2 u[5];
#pragma unroll
    for (int r = 0; r < 5; ++r) u[r] = a[5 * idx + r];
    bf5s<-1>(u);
    int rv = rev3_5(idx);
#pragma unroll
    for (int r = 0; r < 5; ++r) a[125 * r + rv] = u[r];
  }
  __syncthreads();
  // chained epilogue over 512 threads: cc fixed, k2 steps by 128
  int cc = tid & 3, k20 = tid >> 2;   // k20 in [0,128)
  int n1 = n1base + cc;
  float w = -(TWO_PI / (float)L) * (float)n1;
  float2 t = cisf(w * (float)k20);
  float2 stp = cisf(w * 128.0f);
  for (int k2 = k20; k2 < 625; k2 += 128) {
    G[(size_t)sig * L + k2 * 256 + n1] = cmulf(A[cc * 625 + k2], t);
    t = cmulf(t, stp);
  }
}

// ---------- FI: fused f2+i1, 16 rows / 1024 thr / 4 bands per block. ----------
__global__ __launch_bounds__(1024) void fi_kernel(const float2* __restrict__ G,
                                                  __half2* __restrict__ H) {
  __shared__ float2 Xb[16 * RS];   // forward spectra (pad8)
  __shared__ float2 Wb[16 * RS];   // inverse work (stages 1-3)
  int blk = blockIdx.x;            // grid = 2 * BATCH * 40 = 640
  int bg  = blk / (BATCH * 40);    // band-group 0..1 (4 bands each)
  int rem = blk - bg * (BATCH * 40);
  int sig = rem / 40, gr = rem % 40;
  int k2base = gr * 16;
  int tid = threadIdx.x;
  int wv = tid >> 6, ln = tid & 63;
  int k2 = k2base + wv;
  bool act = (k2 < 625);
  float2* xr = Xb + wv * RS;
  float2* wr = Wb + wv * RS;

  // ---- hoisted stage twiddles (inverse sign; forward uses conj) ----
  float2 tw1 = cisf((TWO_PI / 256.0f) * (float)ln);
  float2 tw2 = cisf((TWO_PI / 64.0f) * (float)(ln & 15));
  float2 tw3 = cisf((TWO_PI / 16.0f) * (float)(ln & 3));

  // ---- forward DIF-256 of own row (once per band-group) ----
  if (act) {
#pragma unroll
    for (int r = 0; r < 4; ++r)
      xr[pad8(ln + 64 * r)] = G[(size_t)sig * L + k2 * 256 + ln + 64 * r];
    dif256sw_tw<-1>(xr, ln, conjf(tw1), conjf(tw2), conjf(tw3));
  }

  // ---- hoisted per-lane LDS bases (stage strides are exact in pad8 space) ----
  int b1 = pad8(ln);                              // + 72*r
  int b2 = pad8(64 * (ln >> 4) + (ln & 15));      // + 18*r
  int jb3 = 16 * (ln >> 2) + (ln & 3);            // pad8(jb3 + 4*r)
  int kb = 625 * ln + k2;                         // + 40000*r  (bin number)

  // ---- fused stage-4 + epilogue constants ----
  int cc = tid & 15, q = tid >> 4;                // q in 0..63 (butterfly id)
  int rq = rev3_4(q);                             // n1 = 64*r + rq
  int k2e = k2base + cc;
  bool eact = (k2e < 625);
  float a0 = (TWO_PI / (float)L) * (float)k2e;
  float2 t0q = cisf(a0 * (float)rq);
  float2 stp = cisf(a0 * 64.0f);

#pragma unroll
  for (int bi = 0; bi < 4; ++bi) {
    int band = bg * 4 + bi;
    unsigned lo1, d1, lo2, d2;
    if (band < 7) {
      lo1 = 10000u * band + 1u;              d1 = 9999u;
      lo2 = (unsigned)L - 10000u * (band + 1); d2 = 9999u;
    } else {
      lo1 = 70001u; d1 = 19998u;             // 70001..89999
      lo2 = 0u;     d2 = 0u;                 // DC bin -> band 7
    }
    if (act) {
      float2 u[4];
      // stage 1: read Xb with in-register band mask, write Wb
#pragma unroll
      for (int r = 0; r < 4; ++r) {
        float2 x = xr[b1 + 72 * r];
        unsigned k = (unsigned)(kb + 40000 * r);
        bool in = ((k - lo1) <= d1) || ((k - lo2) <= d2);
        u[r] = in ? x : make_float2(0.0f, 0.0f);
      }
      bf4s<1>(u);
      twchain<4>(u, tw1);
#pragma unroll
      for (int r = 0; r < 4; ++r) wr[b1 + 72 * r] = u[r];
      // stage 2
#pragma unroll
      for (int r = 0; r < 4; ++r) u[r] = wr[b2 + 18 * r];
      bf4s<1>(u);
      twchain<4>(u, tw2);
#pragma unroll
      for (int r = 0; r < 4; ++r) wr[b2 + 18 * r] = u[r];
      // stage 3
#pragma unroll
      for (int r = 0; r < 4; ++r) u[r] = wr[pad8(jb3 + 4 * r)];
      bf4s<1>(u);
      twchain<4>(u, tw3);
#pragma unroll
      for (int r = 0; r < 4; ++r) wr[pad8(jb3 + 4 * r)] = u[r];
    }
    __syncthreads();
    // fused stage 4 + epilogue: butterfly q of row cc, outputs n1 = 64r + rq
    if (eact) {
      size_t obase = (size_t)(sig * NB + band) * L;
      int b4 = cc * RS + pad8(4 * q);             // + r exact (r<4)
      float2 v[4];
#pragma unroll
      for (int r = 0; r < 4; ++r) v[r] = Wb[b4 + r];
      bf4s<1>(v);
      float2 t = t0q;
#pragma unroll
      for (int r = 0; r < 4; ++r) {
        int n1 = 64 * r + rq;
        float2 val = cmulf(v[r], t);
        H[obase + (size_t)n1 * 625 + k2e] = __floats2half2_rn(val.x * INVL, val.y * INVL);
        t = cmulf(t, stp);
      }
    }
    __syncthreads();
  }
}

// ---------- I2: one wave per 2 columns (AA/AB interleaved), fused energy pass.
//              INSTRUMENTED: compute x3, atomics only on last rep. ----------
__global__ __launch_bounds__(256) void i2_kernel(const __half2* __restrict__ H,
                                                 float* __restrict__ E) {
  __shared__ float2 AA[4 * 625];      // 20000 B (column A per wave)
  __shared__ float2 AB[4 * 625];      // 20000 B (column B per wave)
  __shared__ float P[4 * 2 * NHOPS];  // 4992 B
  int blk = blockIdx.x;               // grid = BATCH*NB*32 = 2048
  int g = blk & 31, sb = blk >> 5;
  int band = sb & 7, sig = sb >> 3;
  int tid = threadIdx.x;
  int wv = tid >> 6, ln = tid & 63;
  size_t base = (size_t)(sig * NB + band) * L;
  int n1A = 8 * g + wv, n1B = 8 * g + 4 + wv;
  const __half2* HA = H + base + (size_t)n1A * 625;
  const __half2* HB = H + base + (size_t)n1B * 625;
  int j1 = ln, j2 = ln + 64;
  bool g2 = (j2 < 125);
  __half2 hA1[5], hA2[5], hB1[5], hB2[5];
#pragma unroll
  for (int r = 0; r < 5; ++r) hA1[r] = HA[j1 + 125 * r];
  if (g2) {
#pragma unroll
    for (int r = 0; r < 5; ++r) hA2[r] = HA[j2 + 125 * r];
  }
#pragma unroll
  for (int r = 0; r < 5; ++r) hB1[r] = HB[j1 + 125 * r];
  if (g2) {
#pragma unroll
    for (int r = 0; r < 5; ++r) hB2[r] = HB[j2 + 125 * r];
  }
  float2 tS1a = cisf((TWO_PI / 625.0f) * (float)j1);
  float2 tS1b = cisf((TWO_PI / 625.0f) * (float)j2);
  float2 tS2a = cisf((TWO_PI / 125.0f) * (float)(j1 % 25));
  float2 tS2b = cisf((TWO_PI / 125.0f) * (float)(j2 % 25));
  float2 tS3a = cisf((TWO_PI / 25.0f) * (float)(j1 % 5));
  float2 tS3b = cisf((TWO_PI / 25.0f) * (float)(j2 % 5));
  float2* aA = AA + wv * 625;
  float2* aB = AB + wv * 625;
  float* Pw = P + wv * (2 * NHOPS);

#pragma unroll 1
  for (int rep = 0; rep < 3; ++rep) {
    __syncthreads();   // protect AA/AB/P reuse across reps

    // ---- stage 1 (from registers), columns A then B (independent chains) ----
    {
      float2 u[5];
#pragma unroll
      for (int r = 0; r < 5; ++r) u[r] = __half22float2(hA1[r]);
      bf5s<1>(u);
      twchain<5>(u, tS1a);
#pragma unroll
      for (int r = 0; r < 5; ++r) aA[j1 + 125 * r] = u[r];
      if (g2) {
        float2 v[5];
#pragma unroll
        for (int r = 0; r < 5; ++r) v[r] = __half22float2(hA2[r]);
        bf5s<1>(v);
        twchain<5>(v, tS1b);
#pragma unroll
        for (int r = 0; r < 5; ++r) aA[j2 + 125 * r] = v[r];
      }
    }
    {
      float2 u[5];
#pragma unroll
      for (int r = 0; r < 5; ++r) u[r] = __half22float2(hB1[r]);
      bf5s<1>(u);
      twchain<5>(u, tS1a);
#pragma unroll
      for (int r = 0; r < 5; ++r) aB[j1 + 125 * r] = u[r];
      if (g2) {
        float2 v[5];
#pragma unroll
        for (int r = 0; r < 5; ++r) v[r] = __half22float2(hB2[r]);
        bf5s<1>(v);
        twchain<5>(v, tS1b);
#pragma unroll
        for (int r = 0; r < 5; ++r) aB[j2 + 125 * r] = v[r];
      }
    }
    // ---- stages 2-3 interleaved across the two buffers ----
    dif5_ip_stage_t<25>(aA, ln, tS2a, tS2b);
    dif5_ip_stage_t<25>(aB, ln, tS2a, tS2b);
    dif5_ip_stage_t<5>(aA, ln, tS3a, tS3b);
    dif5_ip_stage_t<5>(aB, ln, tS3a, tS3b);
    // ---- final stage, both columns ----
    {
      float2 u[5], v[5];
#pragma unroll
      for (int r = 0; r < 5; ++r) u[r] = aA[5 * j1 + r];
      if (g2) {
#pragma unroll
        for (int r = 0; r < 5; ++r) v[r] = aA[5 * j2 + r];
      }
      bf5s<1>(u);
      if (g2) bf5s<1>(v);
      int rv1 = rev3_5(j1), rv2 = rev3_5(j2);
#pragma unroll
      for (int r = 0; r < 5; ++r) aA[125 * r + rv1] = u[r];
      if (g2) {
#pragma unroll
        for (int r = 0; r < 5; ++r) aA[125 * r + rv2] = v[r];
      }
    }
    {
      float2 u[5], v[5];
#pragma unroll
      for (int r = 0; r < 5; ++r) u[r] = aB[5 * j1 + r];
      if (g2) {
#pragma unroll
        for (int r = 0; r < 5; ++r) v[r] = aB[5 * j2 + r];
      }
      bf5s<1>(u);
      if (g2) bf5s<1>(v);
      int rv1 = rev3_5(j1), rv2 = rev3_5(j2);
#pragma unroll
      for (int r = 0; r < 5; ++r) aB[125 * r + rv1] = u[r];
      if (g2) {
#pragma unroll
        for (int r = 0; r < 5; ++r) aB[125 * r + rv2] = v[r];
      }
    }
    // ---- fused energy pass over both columns ----
    for (int h = ln; h < NHOPS; h += 64) {
      float ex = 0.0f, ey = 0.0f;
#pragma unroll
      for (int d = 0; d < 4; ++d) {
        float2 zA = aA[4 * h + d];
        float2 zB = aB[4 * h + d];
        ex += zA.x * zA.x + zB.x * zB.x;
        ey += zA.y * zA.y + zB.y * zB.y;
      }
      Pw[h] = ex;
      Pw[NHOPS + h] = ey;
    }
    __syncthreads();
    if (rep == 2) {
      int eb = (sig * NB + band) * NHOPS;
      for (int idx = tid; idx < 2 * NHOPS; idx += 256) {
        float v = P[idx] + P[2 * NHOPS + idx] + P[4 * NHOPS + idx] + P[6 * NHOPS + idx];
        int comp = idx / NHOPS, h = idx - comp * NHOPS;
        atomicAdd(&E[comp * (BATCH * NB * NHOPS) + eb + h], v);
      }
    }
  }
}

// ---------- finalize: loudness, diff, softmax (H pre-scaled by 1/L -> SC = 1/2048) ----------
__global__ __launch_bounds__(1024) void finalize_kernel(const float* __restrict__ E,
                                                        float* __restrict__ out) {
  constexpr int ND = BATCH * NB * NCHUNK;  // 9920
  constexpr float SC = 1.0f / 2048.0f;
  __shared__ float diffs[ND];
  __shared__ float sred[1024];
  int tid = threadIdx.x;
  for (int idx = tid; idx < ND; idx += 1024) {
    int sb = idx / NCHUNK;
    int k = idx - sb * NCHUNK;
    float msw = (E[sb * NHOPS + k] + E[sb * NHOPS + k + 1]) * SC;
    float mso = (E[64 * NHOPS + sb * NHOPS + k] + E[64 * NHOPS + sb * NHOPS + k + 1]) * SC;
    float lw = -0.691f + 10.0f * log10f(msw + 1e-12f);
    float lo = -0.691f + 10.0f * log10f(mso + 1e-12f);
    diffs[idx] = lw - lo;
  }
  __syncthreads();
  float mx = -3.4e38f;
  for (int idx = tid; idx < ND; idx += 1024) mx = fmaxf(mx, diffs[idx]);
  sred[tid] = mx;
  __syncthreads();
  for (int s = 512; s > 0; s >>= 1) {
    if (tid < s) sred[tid] = fmaxf(sred[tid], sred[tid + s]);
    __syncthreads();
  }
  float gmax = sred[0];
  __syncthreads();
  float se = 0.0f, swd = 0.0f;
  for (int idx = tid; idx < ND; idx += 1024) {
    float d = diffs[idx];
    float e = expf(d - gmax);
    se += e;
    swd += d * e;
  }
  sred[tid] = se; __syncthreads();
  for (int s = 512; s > 0; s >>= 1) { if (tid < s) sred[tid] += sred[tid + s]; __syncthreads(); }
  float tot = sred[0];
  __syncthreads();
  sred[tid] = swd; __syncthreads();
  for (int s = 512; s > 0; s >>= 1) { if (tid < s) sred[tid] += sred[tid + s]; __syncthreads(); }
  if (tid == 0) out[0] = sred[0] / tot;
}

extern "C" void kernel_launch(void* const* d_in, const int* in_sizes, int n_in,
                              void* d_out, int out_size, void* d_ws, size_t ws_size,
                              hipStream_t stream) {
  (void)in_sizes; (void)n_in; (void)out_size; (void)ws_size;
  char* ws = (char*)d_ws;
  float2*  G = (float2*)ws;                        // 10,240,000 B
  __half2* H = (__half2*)(ws + 10240000);          // 40,960,000 B (fp16)
  float*   E = (float*)(ws + 51200000);            // 79,872 B [2][64][156]
  const float* w = (const float*)d_in[0];
  const float* o = (const float*)d_in[1];

  f1_kernel<<<dim3(BATCH * 64), dim3(512), 0, stream>>>(w, o, G, E);
  fi_kernel<<<dim3(2 * BATCH * 40), dim3(1024), 0, stream>>>(G, H);
  i2_kernel<<<dim3(BATCH * NB * 32), dim3(256), 0, stream>>>(H, E);
  finalize_kernel<<<dim3(1), dim3(1024), 0, stream>>>(E, (float*)d_out);
}

// Round 9
// 148.325 us; speedup vs baseline: 1.2856x; 1.2856x over previous
//
#include <hip/hip_runtime.h>
#include <hip/hip_fp16.h>
#include <math.h>

// N = 160000 = 256 * 625; four-step FFT decomposition.
// R24 = R22 with i2 rebuilt from R23's measurement (i2 = 42 us: 22.9 compute
// + 19 load/atomic; 4.45M LDS bank-conflict cycles/rep; 3 blocks/CU):
//  - single per-wave column buffer (A then B sequential, wave-local ordering)
//  - pad16 swizzle (i + i/16, 625->664 slots) kills the power-of-2 stride
//    conflicts (energy read a[4h] was ~16-way; stage-5/final 2-4 way)
//  - LDS 45KB -> 26.2KB => 6 blocks/CU (24 waves/CU, 2x) for load-latency TLP
// f1: pack w+i*o (float4), 2 waves per 625-column, chained epilogue; zeroes E.
// fi: fused f2+i1, 16 rows / 1024 thr / 4 bands per block (grid 640).
// finalize: standalone 1-block (fused variant hit cross-XCD fence cost, R21).
constexpr int L      = 160000;
constexpr int BATCH  = 8;
constexpr int NB     = 8;
constexpr int NHOPS  = 156;
constexpr int NCHUNK = 155;
constexpr int RS     = 289;   // swizzled row stride (fi)
constexpr int PL     = 664;   // pad16(624)+1 slots for i2 column buffer
constexpr float TWO_PI = 6.28318530717958647692f;
constexpr float INVL = 1.0f / (float)L;

__device__ __forceinline__ float2 cmulf(float2 a, float2 b) {
  return make_float2(a.x * b.x - a.y * b.y, a.x * b.y + a.y * b.x);
}

__device__ __forceinline__ float2 cisf(float a) {
  float s, c;
  __sincosf(a, &s, &c);
  return make_float2(c, s);
}

__device__ __forceinline__ float2 conjf(float2 a) { return make_float2(a.x, -a.y); }

__device__ __forceinline__ int pad8(int i) { return i + (i >> 3); }
__device__ __forceinline__ int pad16(int i) { return i + (i >> 4); }

template <int SIGN>
__device__ __forceinline__ void bf4s(float2* v) {
  float2 t0 = make_float2(v[0].x + v[2].x, v[0].y + v[2].y);
  float2 t1 = make_float2(v[0].x - v[2].x, v[0].y - v[2].y);
  float2 t2 = make_float2(v[1].x + v[3].x, v[1].y + v[3].y);
  float2 t3 = make_float2(v[1].x - v[3].x, v[1].y - v[3].y);
  v[0] = make_float2(t0.x + t2.x, t0.y + t2.y);
  v[2] = make_float2(t0.x - t2.x, t0.y - t2.y);
  if constexpr (SIGN < 0) {
    v[1] = make_float2(t1.x + t3.y, t1.y - t3.x);
    v[3] = make_float2(t1.x - t3.y, t1.y + t3.x);
  } else {
    v[1] = make_float2(t1.x - t3.y, t1.y + t3.x);
    v[3] = make_float2(t1.x + t3.y, t1.y - t3.x);
  }
}

template <int SIGN>
__device__ __forceinline__ void bf5s(float2* v) {
  const float c1 = 0.30901699437494745f, s1 = 0.9510565162951535f;
  const float c2 = -0.8090169943749475f, s2 = 0.5877852522924731f;
  float2 t1 = make_float2(v[1].x + v[4].x, v[1].y + v[4].y);
  float2 t3 = make_float2(v[1].x - v[4].x, v[1].y - v[4].y);
  float2 t2 = make_float2(v[2].x + v[3].x, v[2].y + v[3].y);
  float2 t4 = make_float2(v[2].x - v[3].x, v[2].y - v[3].y);
  float2 a = make_float2(v[0].x + c1 * t1.x + c2 * t2.x, v[0].y + c1 * t1.y + c2 * t2.y);
  float2 b = make_float2(s1 * t3.x + s2 * t4.x, s1 * t3.y + s2 * t4.y);
  float2 c = make_float2(v[0].x + c2 * t1.x + c1 * t2.x, v[0].y + c2 * t1.y + c1 * t2.y);
  float2 d = make_float2(s2 * t3.x - s1 * t4.x, s2 * t3.y - s1 * t4.y);
  v[0] = make_float2(v[0].x + t1.x + t2.x, v[0].y + t1.y + t2.y);
  if constexpr (SIGN < 0) {
    v[1] = make_float2(a.x + b.y, a.y - b.x);
    v[4] = make_float2(a.x - b.y, a.y + b.x);
    v[2] = make_float2(c.x + d.y, c.y - d.x);
    v[3] = make_float2(c.x - d.y, c.y + d.x);
  } else {
    v[1] = make_float2(a.x - b.y, a.y + b.x);
    v[4] = make_float2(a.x + b.y, a.y - b.x);
    v[2] = make_float2(c.x - d.y, c.y + d.x);
    v[3] = make_float2(c.x + d.y, c.y - d.x);
  }
}

template <int R>
__device__ __forceinline__ void twchain(float2* v, float2 t1) {
  float2 t = t1;
  v[1] = cmulf(v[1], t);
#pragma unroll
  for (int r = 2; r < R; ++r) { t = cmulf(t, t1); v[r] = cmulf(v[r], t); }
}

__device__ __forceinline__ int rev3_5(int q) {
  int q5 = q / 5, q25 = q / 25;
  int d0 = q - 5 * q5, d1 = q5 - 5 * q25;
  return 25 * d0 + 5 * d1 + q25;
}

__device__ __forceinline__ int rev3_4(int q) {
  return ((q & 3) << 4) | (q & 12) | (q >> 4);
}

// ---------- single-butterfly DIF-625 stage (128 lanes/column, f1) ----------
template <int SUB, int SIGN>
__device__ __forceinline__ void dif5_stage_1b(float2* a, int idx) {
  int j = idx % SUB;
  int b = (idx / SUB) * (5 * SUB) + j;
  float2 u[5];
#pragma unroll
  for (int r = 0; r < 5; ++r) u[r] = a[b + SUB * r];
  bf5s<SIGN>(u);
  twchain<5>(u, cisf((float)SIGN * (TWO_PI / (float)(5 * SUB)) * (float)j));
#pragma unroll
  for (int r = 0; r < 5; ++r) a[b + SUB * r] = u[r];
}

// ---------- dual-butterfly DIF-625 stage, pad16 LDS, precomputed twiddles (i2) ----------
template <int SUB>
__device__ __forceinline__ void dif5_stage_pad(float2* a, int ln, float2 t1a, float2 t1b) {
  int i1 = ln, i2 = ln + 64;
  bool g2 = (i2 < 125);
  int j1 = i1 % SUB, j2 = i2 % SUB;
  int b1 = (i1 / SUB) * (5 * SUB) + j1;
  int b2 = (i2 / SUB) * (5 * SUB) + j2;
  float2 u[5], v[5];
#pragma unroll
  for (int r = 0; r < 5; ++r) u[r] = a[pad16(b1 + SUB * r)];
  if (g2) {
#pragma unroll
    for (int r = 0; r < 5; ++r) v[r] = a[pad16(b2 + SUB * r)];
  }
  bf5s<1>(u);
  twchain<5>(u, t1a);
  if (g2) {
    bf5s<1>(v);
    twchain<5>(v, t1b);
  }
#pragma unroll
  for (int r = 0; r < 5; ++r) a[pad16(b1 + SUB * r)] = u[r];
  if (g2) {
#pragma unroll
    for (int r = 0; r < 5; ++r) a[pad16(b2 + SUB * r)] = v[r];
  }
}

// ---------- in-place DIF-256, pad8-swizzled, hoisted twiddles (fi) ----------
template <int SIGN>
__device__ __forceinline__ void dif256sw_tw(float2* a, int ln,
                                            float2 tw1, float2 tw2, float2 tw3) {
  {
    int b = pad8(ln);            // + 72*r exact
    float2 u[4];
#pragma unroll
    for (int r = 0; r < 4; ++r) u[r] = a[b + 72 * r];
    bf4s<SIGN>(u);
    twchain<4>(u, tw1);
#pragma unroll
    for (int r = 0; r < 4; ++r) a[b + 72 * r] = u[r];
  }
  {
    int j = ln & 15, b = pad8(64 * (ln >> 4) + j);   // + 18*r exact
    float2 u[4];
#pragma unroll
    for (int r = 0; r < 4; ++r) u[r] = a[b + 18 * r];
    bf4s<SIGN>(u);
    twchain<4>(u, tw2);
#pragma unroll
    for (int r = 0; r < 4; ++r) a[b + 18 * r] = u[r];
  }
  {
    int j = ln & 3, jb = 16 * (ln >> 2) + j;
    float2 u[4];
#pragma unroll
    for (int r = 0; r < 4; ++r) u[r] = a[pad8(jb + 4 * r)];
    bf4s<SIGN>(u);
    twchain<4>(u, tw3);
#pragma unroll
    for (int r = 0; r < 4; ++r) a[pad8(jb + 4 * r)] = u[r];
  }
  {
    float2 u[4];
#pragma unroll
    for (int r = 0; r < 4; ++r) u[r] = a[pad8(4 * ln + r)];
    bf4s<SIGN>(u);
    int rv = rev3_4(ln);
#pragma unroll
    for (int r = 0; r < 4; ++r) a[pad8(64 * r + rv)] = u[r];
  }
}

// ---------- F1: float4 pack, 2 waves per 625-column, chained epilogue; zero E ----------
__global__ __launch_bounds__(512) void f1_kernel(const float* __restrict__ win,
                                                 const float* __restrict__ oin,
                                                 float2* __restrict__ G,
                                                 float* __restrict__ E) {
  __shared__ float2 A[4 * 625];    // 20 KB
  int blk = blockIdx.x;            // grid = BATCH * 64 = 512
  int tid = threadIdx.x;
  int gid = blk * 512 + tid;
  if (gid < 2 * BATCH * NB * NHOPS) E[gid] = 0.0f;   // replaces memset launch
  int sig = blk >> 6, g = blk & 63;
  int n1base = g * 4;
  const float4* wp4 = (const float4*)(win + (size_t)sig * L);
  const float4* op4 = (const float4*)(oin + (size_t)sig * L);
  for (int r = tid; r < 625; r += 512) {
    float4 wv = wp4[r * 64 + g];
    float4 ov = op4[r * 64 + g];
    A[0 * 625 + r] = make_float2(wv.x, ov.x);
    A[1 * 625 + r] = make_float2(wv.y, ov.y);
    A[2 * 625 + r] = make_float2(wv.z, ov.z);
    A[3 * 625 + r] = make_float2(wv.w, ov.w);
  }
  __syncthreads();
  // 2 waves per column: 128 lanes, 1 butterfly each (125 active)
  int col = tid >> 7, idx = tid & 127;
  float2* a = A + col * 625;
  bool act = (idx < 125);
  if (act) dif5_stage_1b<125, -1>(a, idx);
  __syncthreads();
  if (act) dif5_stage_1b<25, -1>(a, idx);
  __syncthreads();
  if (act) dif5_stage_1b<5, -1>(a, idx);
  __syncthreads();
  if (act) {
    float2 u[5];
#pragma unroll
    for (int r = 0; r < 5; ++r) u[r] = a[5 * idx + r];
    bf5s<-1>(u);
    int rv = rev3_5(idx);
#pragma unroll
    for (int r = 0; r < 5; ++r) a[125 * r + rv] = u[r];
  }
  __syncthreads();
  // chained epilogue over 512 threads: cc fixed, k2 steps by 128
  int cc = tid & 3, k20 = tid >> 2;   // k20 in [0,128)
  int n1 = n1base + cc;
  float w = -(TWO_PI / (float)L) * (float)n1;
  float2 t = cisf(w * (float)k20);
  float2 stp = cisf(w * 128.0f);
  for (int k2 = k20; k2 < 625; k2 += 128) {
    G[(size_t)sig * L + k2 * 256 + n1] = cmulf(A[cc * 625 + k2], t);
    t = cmulf(t, stp);
  }
}

// ---------- FI: fused f2+i1, 16 rows / 1024 thr / 4 bands per block. ----------
__global__ __launch_bounds__(1024) void fi_kernel(const float2* __restrict__ G,
                                                  __half2* __restrict__ H) {
  __shared__ float2 Xb[16 * RS];   // forward spectra (pad8)
  __shared__ float2 Wb[16 * RS];   // inverse work (stages 1-3)
  int blk = blockIdx.x;            // grid = 2 * BATCH * 40 = 640
  int bg  = blk / (BATCH * 40);    // band-group 0..1 (4 bands each)
  int rem = blk - bg * (BATCH * 40);
  int sig = rem / 40, gr = rem % 40;
  int k2base = gr * 16;
  int tid = threadIdx.x;
  int wv = tid >> 6, ln = tid & 63;
  int k2 = k2base + wv;
  bool act = (k2 < 625);
  float2* xr = Xb + wv * RS;
  float2* wr = Wb + wv * RS;

  // ---- hoisted stage twiddles (inverse sign; forward uses conj) ----
  float2 tw1 = cisf((TWO_PI / 256.0f) * (float)ln);
  float2 tw2 = cisf((TWO_PI / 64.0f) * (float)(ln & 15));
  float2 tw3 = cisf((TWO_PI / 16.0f) * (float)(ln & 3));

  // ---- forward DIF-256 of own row (once per band-group) ----
  if (act) {
#pragma unroll
    for (int r = 0; r < 4; ++r)
      xr[pad8(ln + 64 * r)] = G[(size_t)sig * L + k2 * 256 + ln + 64 * r];
    dif256sw_tw<-1>(xr, ln, conjf(tw1), conjf(tw2), conjf(tw3));
  }

  // ---- hoisted per-lane LDS bases (stage strides are exact in pad8 space) ----
  int b1 = pad8(ln);                              // + 72*r
  int b2 = pad8(64 * (ln >> 4) + (ln & 15));      // + 18*r
  int jb3 = 16 * (ln >> 2) + (ln & 3);            // pad8(jb3 + 4*r)
  int kb = 625 * ln + k2;                         // + 40000*r  (bin number)

  // ---- fused stage-4 + epilogue constants ----
  int cc = tid & 15, q = tid >> 4;                // q in 0..63 (butterfly id)
  int rq = rev3_4(q);                             // n1 = 64*r + rq
  int k2e = k2base + cc;
  bool eact = (k2e < 625);
  float a0 = (TWO_PI / (float)L) * (float)k2e;
  float2 t0q = cisf(a0 * (float)rq);
  float2 stp = cisf(a0 * 64.0f);

#pragma unroll
  for (int bi = 0; bi < 4; ++bi) {
    int band = bg * 4 + bi;
    unsigned lo1, d1, lo2, d2;
    if (band < 7) {
      lo1 = 10000u * band + 1u;              d1 = 9999u;
      lo2 = (unsigned)L - 10000u * (band + 1); d2 = 9999u;
    } else {
      lo1 = 70001u; d1 = 19998u;             // 70001..89999
      lo2 = 0u;     d2 = 0u;                 // DC bin -> band 7
    }
    if (act) {
      float2 u[4];
      // stage 1: read Xb with in-register band mask, write Wb
#pragma unroll
      for (int r = 0; r < 4; ++r) {
        float2 x = xr[b1 + 72 * r];
        unsigned k = (unsigned)(kb + 40000 * r);
        bool in = ((k - lo1) <= d1) || ((k - lo2) <= d2);
        u[r] = in ? x : make_float2(0.0f, 0.0f);
      }
      bf4s<1>(u);
      twchain<4>(u, tw1);
#pragma unroll
      for (int r = 0; r < 4; ++r) wr[b1 + 72 * r] = u[r];
      // stage 2
#pragma unroll
      for (int r = 0; r < 4; ++r) u[r] = wr[b2 + 18 * r];
      bf4s<1>(u);
      twchain<4>(u, tw2);
#pragma unroll
      for (int r = 0; r < 4; ++r) wr[b2 + 18 * r] = u[r];
      // stage 3
#pragma unroll
      for (int r = 0; r < 4; ++r) u[r] = wr[pad8(jb3 + 4 * r)];
      bf4s<1>(u);
      twchain<4>(u, tw3);
#pragma unroll
      for (int r = 0; r < 4; ++r) wr[pad8(jb3 + 4 * r)] = u[r];
    }
    __syncthreads();
    // fused stage 4 + epilogue: butterfly q of row cc, outputs n1 = 64r + rq
    if (eact) {
      size_t obase = (size_t)(sig * NB + band) * L;
      int b4 = cc * RS + pad8(4 * q);             // + r exact (r<4)
      float2 v[4];
#pragma unroll
      for (int r = 0; r < 4; ++r) v[r] = Wb[b4 + r];
      bf4s<1>(v);
      float2 t = t0q;
#pragma unroll
      for (int r = 0; r < 4; ++r) {
        int n1 = 64 * r + rq;
        float2 val = cmulf(v[r], t);
        H[obase + (size_t)n1 * 625 + k2e] = __floats2half2_rn(val.x * INVL, val.y * INVL);
        t = cmulf(t, stp);
      }
    }
    __syncthreads();
  }
}

// ---------- I2: one wave per 2 columns (sequential, single pad16 buffer),
//              fused energy pass, per-wave LDS partials, single barrier ----------
__global__ __launch_bounds__(256) void i2_kernel(const __half2* __restrict__ H,
                                                 float* __restrict__ E) {
  __shared__ float2 A[4 * PL];        // 21248 B (one padded column per wave)
  __shared__ float P[4 * 2 * NHOPS];  // 4992 B
  int blk = blockIdx.x;               // grid = BATCH*NB*32 = 2048
  int g = blk & 31, sb = blk >> 5;
  int band = sb & 7, sig = sb >> 3;
  int tid = threadIdx.x;
  int wv = tid >> 6, ln = tid & 63;
  size_t base = (size_t)(sig * NB + band) * L;
  int n1A = 8 * g + wv, n1B = 8 * g + 4 + wv;
  const __half2* HA = H + base + (size_t)n1A * 625;
  const __half2* HB = H + base + (size_t)n1B * 625;
  int j1 = ln, j2 = ln + 64;
  bool g2 = (j2 < 125);
  __half2 hA1[5], hA2[5], hB1[5], hB2[5];
#pragma unroll
  for (int r = 0; r < 5; ++r) hA1[r] = HA[j1 + 125 * r];
  if (g2) {
#pragma unroll
    for (int r = 0; r < 5; ++r) hA2[r] = HA[j2 + 125 * r];
  }
#pragma unroll
  for (int r = 0; r < 5; ++r) hB1[r] = HB[j1 + 125 * r];
  if (g2) {
#pragma unroll
    for (int r = 0; r < 5; ++r) hB2[r] = HB[j2 + 125 * r];
  }
  float2 tS1a = cisf((TWO_PI / 625.0f) * (float)j1);
  float2 tS1b = cisf((TWO_PI / 625.0f) * (float)j2);
  float2 tS2a = cisf((TWO_PI / 125.0f) * (float)(j1 % 25));
  float2 tS2b = cisf((TWO_PI / 125.0f) * (float)(j2 % 25));
  float2 tS3a = cisf((TWO_PI / 25.0f) * (float)(j1 % 5));
  float2 tS3b = cisf((TWO_PI / 25.0f) * (float)(j2 % 5));
  float2* a = A + wv * PL;
  float* Pw = P + wv * (2 * NHOPS);
  int rv1 = rev3_5(j1), rv2 = rev3_5(j2);

  // ---- column A ----
  {
    float2 u[5];
#pragma unroll
    for (int r = 0; r < 5; ++r) u[r] = __half22float2(hA1[r]);
    bf5s<1>(u);
    twchain<5>(u, tS1a);
#pragma unroll
    for (int r = 0; r < 5; ++r) a[pad16(j1 + 125 * r)] = u[r];
    if (g2) {
      float2 v[5];
#pragma unroll
      for (int r = 0; r < 5; ++r) v[r] = __half22float2(hA2[r]);
      bf5s<1>(v);
      twchain<5>(v, tS1b);
#pragma unroll
      for (int r = 0; r < 5; ++r) a[pad16(j2 + 125 * r)] = v[r];
    }
  }
  dif5_stage_pad<25>(a, ln, tS2a, tS2b);
  dif5_stage_pad<5>(a, ln, tS3a, tS3b);
  {
    float2 u[5], v[5];
#pragma unroll
    for (int r = 0; r < 5; ++r) u[r] = a[pad16(5 * j1 + r)];
    if (g2) {
#pragma unroll
      for (int r = 0; r < 5; ++r) v[r] = a[pad16(5 * j2 + r)];
    }
    bf5s<1>(u);
    if (g2) bf5s<1>(v);
#pragma unroll
    for (int r = 0; r < 5; ++r) a[pad16(125 * r + rv1)] = u[r];
    if (g2) {
#pragma unroll
      for (int r = 0; r < 5; ++r) a[pad16(125 * r + rv2)] = v[r];
    }
  }
  for (int h = ln; h < NHOPS; h += 64) {
    float ex = 0.0f, ey = 0.0f;
#pragma unroll
    for (int d = 0; d < 4; ++d) {
      float2 z = a[pad16(4 * h + d)];
      ex += z.x * z.x;
      ey += z.y * z.y;
    }
    Pw[h] = ex;
    Pw[NHOPS + h] = ey;
  }

  // ---- column B (same twiddles, same buffer; wave-local ordering) ----
  {
    float2 u[5];
#pragma unroll
    for (int r = 0; r < 5; ++r) u[r] = __half22float2(hB1[r]);
    bf5s<1>(u);
    twchain<5>(u, tS1a);
#pragma unroll
    for (int r = 0; r < 5; ++r) a[pad16(j1 + 125 * r)] = u[r];
    if (g2) {
      float2 v[5];
#pragma unroll
      for (int r = 0; r < 5; ++r) v[r] = __half22float2(hB2[r]);
      bf5s<1>(v);
      twchain<5>(v, tS1b);
#pragma unroll
      for (int r = 0; r < 5; ++r) a[pad16(j2 + 125 * r)] = v[r];
    }
  }
  dif5_stage_pad<25>(a, ln, tS2a, tS2b);
  dif5_stage_pad<5>(a, ln, tS3a, tS3b);
  {
    float2 u[5], v[5];
#pragma unroll
    for (int r = 0; r < 5; ++r) u[r] = a[pad16(5 * j1 + r)];
    if (g2) {
#pragma unroll
      for (int r = 0; r < 5; ++r) v[r] = a[pad16(5 * j2 + r)];
    }
    bf5s<1>(u);
    if (g2) bf5s<1>(v);
#pragma unroll
    for (int r = 0; r < 5; ++r) a[pad16(125 * r + rv1)] = u[r];
    if (g2) {
#pragma unroll
      for (int r = 0; r < 5; ++r) a[pad16(125 * r + rv2)] = v[r];
    }
  }
  for (int h = ln; h < NHOPS; h += 64) {
    float ex = 0.0f, ey = 0.0f;
#pragma unroll
    for (int d = 0; d < 4; ++d) {
      float2 z = a[pad16(4 * h + d)];
      ex += z.x * z.x;
      ey += z.y * z.y;
    }
    Pw[h] += ex;
    Pw[NHOPS + h] += ey;
  }
  __syncthreads();   // the only block-wide barrier
  int eb = (sig * NB + band) * NHOPS;
  for (int idx = tid; idx < 2 * NHOPS; idx += 256) {
    float v = P[idx] + P[2 * NHOPS + idx] + P[4 * NHOPS + idx] + P[6 * NHOPS + idx];
    int comp = idx / NHOPS, h = idx - comp * NHOPS;
    atomicAdd(&E[comp * (BATCH * NB * NHOPS) + eb + h], v);
  }
}

// ---------- finalize: loudness, diff, softmax (H pre-scaled by 1/L -> SC = 1/2048) ----------
__global__ __launch_bounds__(1024) void finalize_kernel(const float* __restrict__ E,
                                                        float* __restrict__ out) {
  constexpr int ND = BATCH * NB * NCHUNK;  // 9920
  constexpr float SC = 1.0f / 2048.0f;
  __shared__ float diffs[ND];
  __shared__ float sred[1024];
  int tid = threadIdx.x;
  for (int idx = tid; idx < ND; idx += 1024) {
    int sb = idx / NCHUNK;
    int k = idx - sb * NCHUNK;
    float msw = (E[sb * NHOPS + k] + E[sb * NHOPS + k + 1]) * SC;
    float mso = (E[64 * NHOPS + sb * NHOPS + k] + E[64 * NHOPS + sb * NHOPS + k + 1]) * SC;
    float lw = -0.691f + 10.0f * log10f(msw + 1e-12f);
    float lo = -0.691f + 10.0f * log10f(mso + 1e-12f);
    diffs[idx] = lw - lo;
  }
  __syncthreads();
  float mx = -3.4e38f;
  for (int idx = tid; idx < ND; idx += 1024) mx = fmaxf(mx, diffs[idx]);
  sred[tid] = mx;
  __syncthreads();
  for (int s = 512; s > 0; s >>= 1) {
    if (tid < s) sred[tid] = fmaxf(sred[tid], sred[tid + s]);
    __syncthreads();
  }
  float gmax = sred[0];
  __syncthreads();
  float se = 0.0f, swd = 0.0f;
  for (int idx = tid; idx < ND; idx += 1024) {
    float d = diffs[idx];
    float e = expf(d - gmax);
    se += e;
    swd += d * e;
  }
  sred[tid] = se; __syncthreads();
  for (int s = 512; s > 0; s >>= 1) { if (tid < s) sred[tid] += sred[tid + s]; __syncthreads(); }
  float tot = sred[0];
  __syncthreads();
  sred[tid] = swd; __syncthreads();
  for (int s = 512; s > 0; s >>= 1) { if (tid < s) sred[tid] += sred[tid + s]; __syncthreads(); }
  if (tid == 0) out[0] = sred[0] / tot;
}

extern "C" void kernel_launch(void* const* d_in, const int* in_sizes, int n_in,
                              void* d_out, int out_size, void* d_ws, size_t ws_size,
                              hipStream_t stream) {
  (void)in_sizes; (void)n_in; (void)out_size; (void)ws_size;
  char* ws = (char*)d_ws;
  float2*  G = (float2*)ws;                        // 10,240,000 B
  __half2* H = (__half2*)(ws + 10240000);          // 40,960,000 B (fp16)
  float*   E = (float*)(ws + 51200000);            // 79,872 B [2][64][156]
  const float* w = (const float*)d_in[0];
  const float* o = (const float*)d_in[1];

  f1_kernel<<<dim3(BATCH * 64), dim3(512), 0, stream>>>(w, o, G, E);
  fi_kernel<<<dim3(2 * BATCH * 40), dim3(1024), 0, stream>>>(G, H);
  i2_kernel<<<dim3(BATCH * NB * 32), dim3(256), 0, stream>>>(H, E);
  finalize_kernel<<<dim3(1), dim3(1024), 0, stream>>>(E, (float*)d_out);
}

// Round 10
// 142.744 us; speedup vs baseline: 1.3359x; 1.0391x over previous
//
#include <hip/hip_runtime.h>
#include <hip/hip_fp16.h>
#include <math.h>

// N = 160000 = 256 * 625; four-step FFT decomposition.
// R25 = R22 retuned to the block-scheduling-tail model (R23/R24 measurements):
//  - i2: R22's dual-buffer FFT kept verbatim; P[] eliminated (hop energies in
//    registers, spilled into dead AA for the cross-wave reduce). LDS = exactly
//    40000 B -> 4 blocks/CU -> 1024 slots -> 2048 blocks = 2 EXACT rounds
//    (R22: 45KB -> 3/CU -> 2.67 rounds; R24: 6/CU -> 1.33 rounds, both tailed).
//  - fi: back to 4 band-groups x 2 bands (grid 1280 = 2.5->3 rounds @ 83% util;
//    beats grid 640's 62.5% despite 640 doing less forward-FFT recompute).
// f1: pack w+i*o (float4), 2 waves per 625-column, chained epilogue; zeroes E.
// finalize: standalone 1-block (fused variant hit cross-XCD fence cost, R21).
constexpr int L      = 160000;
constexpr int BATCH  = 8;
constexpr int NB     = 8;
constexpr int NHOPS  = 156;
constexpr int NCHUNK = 155;
constexpr int RS     = 289;   // swizzled row stride (fi)
constexpr float TWO_PI = 6.28318530717958647692f;
constexpr float INVL = 1.0f / (float)L;

__device__ __forceinline__ float2 cmulf(float2 a, float2 b) {
  return make_float2(a.x * b.x - a.y * b.y, a.x * b.y + a.y * b.x);
}

__device__ __forceinline__ float2 cisf(float a) {
  float s, c;
  __sincosf(a, &s, &c);
  return make_float2(c, s);
}

__device__ __forceinline__ float2 conjf(float2 a) { return make_float2(a.x, -a.y); }

__device__ __forceinline__ int pad8(int i) { return i + (i >> 3); }

template <int SIGN>
__device__ __forceinline__ void bf4s(float2* v) {
  float2 t0 = make_float2(v[0].x + v[2].x, v[0].y + v[2].y);
  float2 t1 = make_float2(v[0].x - v[2].x, v[0].y - v[2].y);
  float2 t2 = make_float2(v[1].x + v[3].x, v[1].y + v[3].y);
  float2 t3 = make_float2(v[1].x - v[3].x, v[1].y - v[3].y);
  v[0] = make_float2(t0.x + t2.x, t0.y + t2.y);
  v[2] = make_float2(t0.x - t2.x, t0.y - t2.y);
  if constexpr (SIGN < 0) {
    v[1] = make_float2(t1.x + t3.y, t1.y - t3.x);
    v[3] = make_float2(t1.x - t3.y, t1.y + t3.x);
  } else {
    v[1] = make_float2(t1.x - t3.y, t1.y + t3.x);
    v[3] = make_float2(t1.x + t3.y, t1.y - t3.x);
  }
}

template <int SIGN>
__device__ __forceinline__ void bf5s(float2* v) {
  const float c1 = 0.30901699437494745f, s1 = 0.9510565162951535f;
  const float c2 = -0.8090169943749475f, s2 = 0.5877852522924731f;
  float2 t1 = make_float2(v[1].x + v[4].x, v[1].y + v[4].y);
  float2 t3 = make_float2(v[1].x - v[4].x, v[1].y - v[4].y);
  float2 t2 = make_float2(v[2].x + v[3].x, v[2].y + v[3].y);
  float2 t4 = make_float2(v[2].x - v[3].x, v[2].y - v[3].y);
  float2 a = make_float2(v[0].x + c1 * t1.x + c2 * t2.x, v[0].y + c1 * t1.y + c2 * t2.y);
  float2 b = make_float2(s1 * t3.x + s2 * t4.x, s1 * t3.y + s2 * t4.y);
  float2 c = make_float2(v[0].x + c2 * t1.x + c1 * t2.x, v[0].y + c2 * t1.y + c1 * t2.y);
  float2 d = make_float2(s2 * t3.x - s1 * t4.x, s2 * t3.y - s1 * t4.y);
  v[0] = make_float2(v[0].x + t1.x + t2.x, v[0].y + t1.y + t2.y);
  if constexpr (SIGN < 0) {
    v[1] = make_float2(a.x + b.y, a.y - b.x);
    v[4] = make_float2(a.x - b.y, a.y + b.x);
    v[2] = make_float2(c.x + d.y, c.y - d.x);
    v[3] = make_float2(c.x - d.y, c.y + d.x);
  } else {
    v[1] = make_float2(a.x - b.y, a.y + b.x);
    v[4] = make_float2(a.x + b.y, a.y - b.x);
    v[2] = make_float2(c.x - d.y, c.y + d.x);
    v[3] = make_float2(c.x + d.y, c.y - d.x);
  }
}

template <int R>
__device__ __forceinline__ void twchain(float2* v, float2 t1) {
  float2 t = t1;
  v[1] = cmulf(v[1], t);
#pragma unroll
  for (int r = 2; r < R; ++r) { t = cmulf(t, t1); v[r] = cmulf(v[r], t); }
}

__device__ __forceinline__ int rev3_5(int q) {
  int q5 = q / 5, q25 = q / 25;
  int d0 = q - 5 * q5, d1 = q5 - 5 * q25;
  return 25 * d0 + 5 * d1 + q25;
}

__device__ __forceinline__ int rev3_4(int q) {
  return ((q & 3) << 4) | (q & 12) | (q >> 4);
}

// ---------- single-butterfly DIF-625 stage (128 lanes/column, f1) ----------
template <int SUB, int SIGN>
__device__ __forceinline__ void dif5_stage_1b(float2* a, int idx) {
  int j = idx % SUB;
  int b = (idx / SUB) * (5 * SUB) + j;
  float2 u[5];
#pragma unroll
  for (int r = 0; r < 5; ++r) u[r] = a[b + SUB * r];
  bf5s<SIGN>(u);
  twchain<5>(u, cisf((float)SIGN * (TWO_PI / (float)(5 * SUB)) * (float)j));
#pragma unroll
  for (int r = 0; r < 5; ++r) a[b + SUB * r] = u[r];
}

// ---------- dual-butterfly DIF-625 stage, precomputed twiddles (i2) ----------
template <int SUB>
__device__ __forceinline__ void dif5_ip_stage_t(float2* a, int ln, float2 t1a, float2 t1b) {
  int i1 = ln, i2 = ln + 64;
  bool g2 = (i2 < 125);
  int j1 = i1 % SUB, j2 = i2 % SUB;
  int b1 = (i1 / SUB) * (5 * SUB) + j1;
  int b2 = (i2 / SUB) * (5 * SUB) + j2;
  float2 u[5], v[5];
#pragma unroll
  for (int r = 0; r < 5; ++r) u[r] = a[b1 + SUB * r];
  if (g2) {
#pragma unroll
    for (int r = 0; r < 5; ++r) v[r] = a[b2 + SUB * r];
  }
  bf5s<1>(u);
  twchain<5>(u, t1a);
  if (g2) {
    bf5s<1>(v);
    twchain<5>(v, t1b);
  }
#pragma unroll
  for (int r = 0; r < 5; ++r) a[b1 + SUB * r] = u[r];
  if (g2) {
#pragma unroll
    for (int r = 0; r < 5; ++r) a[b2 + SUB * r] = v[r];
  }
}

// ---------- in-place DIF-256, pad8-swizzled, hoisted twiddles (fi) ----------
template <int SIGN>
__device__ __forceinline__ void dif256sw_tw(float2* a, int ln,
                                            float2 tw1, float2 tw2, float2 tw3) {
  {
    int b = pad8(ln);            // + 72*r exact
    float2 u[4];
#pragma unroll
    for (int r = 0; r < 4; ++r) u[r] = a[b + 72 * r];
    bf4s<SIGN>(u);
    twchain<4>(u, tw1);
#pragma unroll
    for (int r = 0; r < 4; ++r) a[b + 72 * r] = u[r];
  }
  {
    int j = ln & 15, b = pad8(64 * (ln >> 4) + j);   // + 18*r exact
    float2 u[4];
#pragma unroll
    for (int r = 0; r < 4; ++r) u[r] = a[b + 18 * r];
    bf4s<SIGN>(u);
    twchain<4>(u, tw2);
#pragma unroll
    for (int r = 0; r < 4; ++r) a[b + 18 * r] = u[r];
  }
  {
    int j = ln & 3, jb = 16 * (ln >> 2) + j;
    float2 u[4];
#pragma unroll
    for (int r = 0; r < 4; ++r) u[r] = a[pad8(jb + 4 * r)];
    bf4s<SIGN>(u);
    twchain<4>(u, tw3);
#pragma unroll
    for (int r = 0; r < 4; ++r) a[pad8(jb + 4 * r)] = u[r];
  }
  {
    float2 u[4];
#pragma unroll
    for (int r = 0; r < 4; ++r) u[r] = a[pad8(4 * ln + r)];
    bf4s<SIGN>(u);
    int rv = rev3_4(ln);
#pragma unroll
    for (int r = 0; r < 4; ++r) a[pad8(64 * r + rv)] = u[r];
  }
}

// ---------- F1: float4 pack, 2 waves per 625-column, chained epilogue; zero E ----------
__global__ __launch_bounds__(512) void f1_kernel(const float* __restrict__ win,
                                                 const float* __restrict__ oin,
                                                 float2* __restrict__ G,
                                                 float* __restrict__ E) {
  __shared__ float2 A[4 * 625];    // 20 KB
  int blk = blockIdx.x;            // grid = BATCH * 64 = 512
  int tid = threadIdx.x;
  int gid = blk * 512 + tid;
  if (gid < 2 * BATCH * NB * NHOPS) E[gid] = 0.0f;   // replaces memset launch
  int sig = blk >> 6, g = blk & 63;
  int n1base = g * 4;
  const float4* wp4 = (const float4*)(win + (size_t)sig * L);
  const float4* op4 = (const float4*)(oin + (size_t)sig * L);
  for (int r = tid; r < 625; r += 512) {
    float4 wv = wp4[r * 64 + g];
    float4 ov = op4[r * 64 + g];
    A[0 * 625 + r] = make_float2(wv.x, ov.x);
    A[1 * 625 + r] = make_float2(wv.y, ov.y);
    A[2 * 625 + r] = make_float2(wv.z, ov.z);
    A[3 * 625 + r] = make_float2(wv.w, ov.w);
  }
  __syncthreads();
  // 2 waves per column: 128 lanes, 1 butterfly each (125 active)
  int col = tid >> 7, idx = tid & 127;
  float2* a = A + col * 625;
  bool act = (idx < 125);
  if (act) dif5_stage_1b<125, -1>(a, idx);
  __syncthreads();
  if (act) dif5_stage_1b<25, -1>(a, idx);
  __syncthreads();
  if (act) dif5_stage_1b<5, -1>(a, idx);
  __syncthreads();
  if (act) {
    float2 u[5];
#pragma unroll
    for (int r = 0; r < 5; ++r) u[r] = a[5 * idx + r];
    bf5s<-1>(u);
    int rv = rev3_5(idx);
#pragma unroll
    for (int r = 0; r < 5; ++r) a[125 * r + rv] = u[r];
  }
  __syncthreads();
  // chained epilogue over 512 threads: cc fixed, k2 steps by 128
  int cc = tid & 3, k20 = tid >> 2;   // k20 in [0,128)
  int n1 = n1base + cc;
  float w = -(TWO_PI / (float)L) * (float)n1;
  float2 t = cisf(w * (float)k20);
  float2 stp = cisf(w * 128.0f);
  for (int k2 = k20; k2 < 625; k2 += 128) {
    G[(size_t)sig * L + k2 * 256 + n1] = cmulf(A[cc * 625 + k2], t);
    t = cmulf(t, stp);
  }
}

// ---------- FI: fused f2+i1, 16 rows / 1024 thr / 2 bands per block (grid 1280). ----------
__global__ __launch_bounds__(1024) void fi_kernel(const float2* __restrict__ G,
                                                  __half2* __restrict__ H) {
  __shared__ float2 Xb[16 * RS];   // forward spectra (pad8)
  __shared__ float2 Wb[16 * RS];   // inverse work (stages 1-3)
  int blk = blockIdx.x;            // grid = 4 * BATCH * 40 = 1280
  int bg  = blk / (BATCH * 40);    // band-group 0..3 (2 bands each)
  int rem = blk - bg * (BATCH * 40);
  int sig = rem / 40, gr = rem % 40;
  int k2base = gr * 16;
  int tid = threadIdx.x;
  int wv = tid >> 6, ln = tid & 63;
  int k2 = k2base + wv;
  bool act = (k2 < 625);
  float2* xr = Xb + wv * RS;
  float2* wr = Wb + wv * RS;

  // ---- hoisted stage twiddles (inverse sign; forward uses conj) ----
  float2 tw1 = cisf((TWO_PI / 256.0f) * (float)ln);
  float2 tw2 = cisf((TWO_PI / 64.0f) * (float)(ln & 15));
  float2 tw3 = cisf((TWO_PI / 16.0f) * (float)(ln & 3));

  // ---- forward DIF-256 of own row (once per band-group) ----
  if (act) {
#pragma unroll
    for (int r = 0; r < 4; ++r)
      xr[pad8(ln + 64 * r)] = G[(size_t)sig * L + k2 * 256 + ln + 64 * r];
    dif256sw_tw<-1>(xr, ln, conjf(tw1), conjf(tw2), conjf(tw3));
  }

  // ---- hoisted per-lane LDS bases (stage strides are exact in pad8 space) ----
  int b1 = pad8(ln);                              // + 72*r
  int b2 = pad8(64 * (ln >> 4) + (ln & 15));      // + 18*r
  int jb3 = 16 * (ln >> 2) + (ln & 3);            // pad8(jb3 + 4*r)
  int kb = 625 * ln + k2;                         // + 40000*r  (bin number)

  // ---- fused stage-4 + epilogue constants ----
  int cc = tid & 15, q = tid >> 4;                // q in 0..63 (butterfly id)
  int rq = rev3_4(q);                             // n1 = 64*r + rq
  int k2e = k2base + cc;
  bool eact = (k2e < 625);
  float a0 = (TWO_PI / (float)L) * (float)k2e;
  float2 t0q = cisf(a0 * (float)rq);
  float2 stp = cisf(a0 * 64.0f);

#pragma unroll
  for (int bi = 0; bi < 2; ++bi) {
    int band = bg * 2 + bi;
    unsigned lo1, d1, lo2, d2;
    if (band < 7) {
      lo1 = 10000u * band + 1u;              d1 = 9999u;
      lo2 = (unsigned)L - 10000u * (band + 1); d2 = 9999u;
    } else {
      lo1 = 70001u; d1 = 19998u;             // 70001..89999
      lo2 = 0u;     d2 = 0u;                 // DC bin -> band 7
    }
    if (act) {
      float2 u[4];
      // stage 1: read Xb with in-register band mask, write Wb
#pragma unroll
      for (int r = 0; r < 4; ++r) {
        float2 x = xr[b1 + 72 * r];
        unsigned k = (unsigned)(kb + 40000 * r);
        bool in = ((k - lo1) <= d1) || ((k - lo2) <= d2);
        u[r] = in ? x : make_float2(0.0f, 0.0f);
      }
      bf4s<1>(u);
      twchain<4>(u, tw1);
#pragma unroll
      for (int r = 0; r < 4; ++r) wr[b1 + 72 * r] = u[r];
      // stage 2
#pragma unroll
      for (int r = 0; r < 4; ++r) u[r] = wr[b2 + 18 * r];
      bf4s<1>(u);
      twchain<4>(u, tw2);
#pragma unroll
      for (int r = 0; r < 4; ++r) wr[b2 + 18 * r] = u[r];
      // stage 3
#pragma unroll
      for (int r = 0; r < 4; ++r) u[r] = wr[pad8(jb3 + 4 * r)];
      bf4s<1>(u);
      twchain<4>(u, tw3);
#pragma unroll
      for (int r = 0; r < 4; ++r) wr[pad8(jb3 + 4 * r)] = u[r];
    }
    __syncthreads();
    // fused stage 4 + epilogue: butterfly q of row cc, outputs n1 = 64r + rq
    if (eact) {
      size_t obase = (size_t)(sig * NB + band) * L;
      int b4 = cc * RS + pad8(4 * q);             // + r exact (r<4)
      float2 v[4];
#pragma unroll
      for (int r = 0; r < 4; ++r) v[r] = Wb[b4 + r];
      bf4s<1>(v);
      float2 t = t0q;
#pragma unroll
      for (int r = 0; r < 4; ++r) {
        int n1 = 64 * r + rq;
        float2 val = cmulf(v[r], t);
        H[obase + (size_t)n1 * 625 + k2e] = __floats2half2_rn(val.x * INVL, val.y * INVL);
        t = cmulf(t, stp);
      }
    }
    __syncthreads();
  }
}

// ---------- I2: one wave per 2 columns (AA/AB interleaved), energy in
//              registers, partials spilled into dead AA; LDS = 40000 B
//              -> 4 blocks/CU -> 2048 blocks = exactly 2 rounds. ----------
__global__ __launch_bounds__(256) void i2_kernel(const __half2* __restrict__ H,
                                                 float* __restrict__ E) {
  __shared__ float2 AA[4 * 625];      // 20000 B (column A per wave)
  __shared__ float2 AB[4 * 625];      // 20000 B (column B per wave)
  int blk = blockIdx.x;               // grid = BATCH*NB*32 = 2048
  int g = blk & 31, sb = blk >> 5;
  int band = sb & 7, sig = sb >> 3;
  int tid = threadIdx.x;
  int wv = tid >> 6, ln = tid & 63;
  size_t base = (size_t)(sig * NB + band) * L;
  int n1A = 8 * g + wv, n1B = 8 * g + 4 + wv;
  const __half2* HA = H + base + (size_t)n1A * 625;
  const __half2* HB = H + base + (size_t)n1B * 625;
  int j1 = ln, j2 = ln + 64;
  bool g2 = (j2 < 125);
  __half2 hA1[5], hA2[5], hB1[5], hB2[5];
#pragma unroll
  for (int r = 0; r < 5; ++r) hA1[r] = HA[j1 + 125 * r];
  if (g2) {
#pragma unroll
    for (int r = 0; r < 5; ++r) hA2[r] = HA[j2 + 125 * r];
  }
#pragma unroll
  for (int r = 0; r < 5; ++r) hB1[r] = HB[j1 + 125 * r];
  if (g2) {
#pragma unroll
    for (int r = 0; r < 5; ++r) hB2[r] = HB[j2 + 125 * r];
  }
  float2 tS1a = cisf((TWO_PI / 625.0f) * (float)j1);
  float2 tS1b = cisf((TWO_PI / 625.0f) * (float)j2);
  float2 tS2a = cisf((TWO_PI / 125.0f) * (float)(j1 % 25));
  float2 tS2b = cisf((TWO_PI / 125.0f) * (float)(j2 % 25));
  float2 tS3a = cisf((TWO_PI / 25.0f) * (float)(j1 % 5));
  float2 tS3b = cisf((TWO_PI / 25.0f) * (float)(j2 % 5));
  float2* aA = AA + wv * 625;
  float2* aB = AB + wv * 625;

  // ---- stage 1 (from registers), columns A then B (independent chains) ----
  {
    float2 u[5];
#pragma unroll
    for (int r = 0; r < 5; ++r) u[r] = __half22float2(hA1[r]);
    bf5s<1>(u);
    twchain<5>(u, tS1a);
#pragma unroll
    for (int r = 0; r < 5; ++r) aA[j1 + 125 * r] = u[r];
    if (g2) {
      float2 v[5];
#pragma unroll
      for (int r = 0; r < 5; ++r) v[r] = __half22float2(hA2[r]);
      bf5s<1>(v);
      twchain<5>(v, tS1b);
#pragma unroll
      for (int r = 0; r < 5; ++r) aA[j2 + 125 * r] = v[r];
    }
  }
  {
    float2 u[5];
#pragma unroll
    for (int r = 0; r < 5; ++r) u[r] = __half22float2(hB1[r]);
    bf5s<1>(u);
    twchain<5>(u, tS1a);
#pragma unroll
    for (int r = 0; r < 5; ++r) aB[j1 + 125 * r] = u[r];
    if (g2) {
      float2 v[5];
#pragma unroll
      for (int r = 0; r < 5; ++r) v[r] = __half22float2(hB2[r]);
      bf5s<1>(v);
      twchain<5>(v, tS1b);
#pragma unroll
      for (int r = 0; r < 5; ++r) aB[j2 + 125 * r] = v[r];
    }
  }
  // ---- stages 2-3 interleaved across the two buffers ----
  dif5_ip_stage_t<25>(aA, ln, tS2a, tS2b);
  dif5_ip_stage_t<25>(aB, ln, tS2a, tS2b);
  dif5_ip_stage_t<5>(aA, ln, tS3a, tS3b);
  dif5_ip_stage_t<5>(aB, ln, tS3a, tS3b);
  // ---- final stage, both columns ----
  {
    float2 u[5], v[5];
#pragma unroll
    for (int r = 0; r < 5; ++r) u[r] = aA[5 * j1 + r];
    if (g2) {
#pragma unroll
      for (int r = 0; r < 5; ++r) v[r] = aA[5 * j2 + r];
    }
    bf5s<1>(u);
    if (g2) bf5s<1>(v);
    int rv1 = rev3_5(j1), rv2 = rev3_5(j2);
#pragma unroll
    for (int r = 0; r < 5; ++r) aA[125 * r + rv1] = u[r];
    if (g2) {
#pragma unroll
      for (int r = 0; r < 5; ++r) aA[125 * r + rv2] = v[r];
    }
  }
  {
    float2 u[5], v[5];
#pragma unroll
    for (int r = 0; r < 5; ++r) u[r] = aB[5 * j1 + r];
    if (g2) {
#pragma unroll
      for (int r = 0; r < 5; ++r) v[r] = aB[5 * j2 + r];
    }
    bf5s<1>(u);
    if (g2) bf5s<1>(v);
    int rv1 = rev3_5(j1), rv2 = rev3_5(j2);
#pragma unroll
    for (int r = 0; r < 5; ++r) aB[125 * r + rv1] = u[r];
    if (g2) {
#pragma unroll
      for (int r = 0; r < 5; ++r) aB[125 * r + rv2] = v[r];
    }
  }
  // ---- fused energy pass over both columns, into registers ----
  float ex[3] = {0.0f, 0.0f, 0.0f}, ey[3] = {0.0f, 0.0f, 0.0f};
#pragma unroll
  for (int k = 0; k < 3; ++k) {
    int h = ln + 64 * k;
    if (h < NHOPS) {
#pragma unroll
      for (int d = 0; d < 4; ++d) {
        float2 zA = aA[4 * h + d];
        float2 zB = aB[4 * h + d];
        ex[k] += zA.x * zA.x + zB.x * zB.x;
        ey[k] += zA.y * zA.y + zB.y * zB.y;
      }
    }
  }
  __syncthreads();                       // all waves done with AA/AB
  float* Ps = (float*)AA;                // 4 waves x 312 floats = 4992 B scratch
#pragma unroll
  for (int k = 0; k < 3; ++k) {
    int h = ln + 64 * k;
    if (h < NHOPS) {
      Ps[wv * (2 * NHOPS) + h] = ex[k];
      Ps[wv * (2 * NHOPS) + NHOPS + h] = ey[k];
    }
  }
  __syncthreads();
  int eb = (sig * NB + band) * NHOPS;
  for (int idx = tid; idx < 2 * NHOPS; idx += 256) {
    float v = Ps[idx] + Ps[2 * NHOPS + idx] + Ps[4 * NHOPS + idx] + Ps[6 * NHOPS + idx];
    int comp = idx / NHOPS, h = idx - comp * NHOPS;
    atomicAdd(&E[comp * (BATCH * NB * NHOPS) + eb + h], v);
  }
}

// ---------- finalize: loudness, diff, softmax (H pre-scaled by 1/L -> SC = 1/2048) ----------
__global__ __launch_bounds__(1024) void finalize_kernel(const float* __restrict__ E,
                                                        float* __restrict__ out) {
  constexpr int ND = BATCH * NB * NCHUNK;  // 9920
  constexpr float SC = 1.0f / 2048.0f;
  __shared__ float diffs[ND];
  __shared__ float sred[1024];
  int tid = threadIdx.x;
  for (int idx = tid; idx < ND; idx += 1024) {
    int sb = idx / NCHUNK;
    int k = idx - sb * NCHUNK;
    float msw = (E[sb * NHOPS + k] + E[sb * NHOPS + k + 1]) * SC;
    float mso = (E[64 * NHOPS + sb * NHOPS + k] + E[64 * NHOPS + sb * NHOPS + k + 1]) * SC;
    float lw = -0.691f + 10.0f * log10f(msw + 1e-12f);
    float lo = -0.691f + 10.0f * log10f(mso + 1e-12f);
    diffs[idx] = lw - lo;
  }
  __syncthreads();
  float mx = -3.4e38f;
  for (int idx = tid; idx < ND; idx += 1024) mx = fmaxf(mx, diffs[idx]);
  sred[tid] = mx;
  __syncthreads();
  for (int s = 512; s > 0; s >>= 1) {
    if (tid < s) sred[tid] = fmaxf(sred[tid], sred[tid + s]);
    __syncthreads();
  }
  float gmax = sred[0];
  __syncthreads();
  float se = 0.0f, swd = 0.0f;
  for (int idx = tid; idx < ND; idx += 1024) {
    float d = diffs[idx];
    float e = expf(d - gmax);
    se += e;
    swd += d * e;
  }
  sred[tid] = se; __syncthreads();
  for (int s = 512; s > 0; s >>= 1) { if (tid < s) sred[tid] += sred[tid + s]; __syncthreads(); }
  float tot = sred[0];
  __syncthreads();
  sred[tid] = swd; __syncthreads();
  for (int s = 512; s > 0; s >>= 1) { if (tid < s) sred[tid] += sred[tid + s]; __syncthreads(); }
  if (tid == 0) out[0] = sred[0] / tot;
}

extern "C" void kernel_launch(void* const* d_in, const int* in_sizes, int n_in,
                              void* d_out, int out_size, void* d_ws, size_t ws_size,
                              hipStream_t stream) {
  (void)in_sizes; (void)n_in; (void)out_size; (void)ws_size;
  char* ws = (char*)d_ws;
  float2*  G = (float2*)ws;                        // 10,240,000 B
  __half2* H = (__half2*)(ws + 10240000);          // 40,960,000 B (fp16)
  float*   E = (float*)(ws + 51200000);            // 79,872 B [2][64][156]
  const float* w = (const float*)d_in[0];
  const float* o = (const float*)d_in[1];

  f1_kernel<<<dim3(BATCH * 64), dim3(512), 0, stream>>>(w, o, G, E);
  fi_kernel<<<dim3(4 * BATCH * 40), dim3(1024), 0, stream>>>(G, H);
  i2_kernel<<<dim3(BATCH * NB * 32), dim3(256), 0, stream>>>(H, E);
  finalize_kernel<<<dim3(1), dim3(1024), 0, stream>>>(E, (float*)d_out);
}

// Round 11
// 142.156 us; speedup vs baseline: 1.3414x; 1.0041x over previous
//
#include <hip/hip_runtime.h>
#include <hip/hip_fp16.h>
#include <math.h>

// N = 160000 = 256 * 625; four-step FFT decomposition.
// R26 = R25 with i2 re-parallelized: ONE column per wave (was 2), 4 columns /
// 256-thr block, grid = BATCH*NB*64 = 4096. LDS exactly 20000 B -> 8 blocks/CU
// (LDS and thread caps both exact) = 32 waves/CU (2x R25), 4096 blocks = 2
// exact rounds of 2048 slots. __launch_bounds__(256,8) pins VGPR <= 64.
// Theory: i2's compute is LDS-latency-chain bound; halving per-wave serial
// work and doubling resident waves attacks the chain directly.
// f1: pack w+i*o (float4), 2 waves per 625-column, chained epilogue; zeroes E.
// fi: fused f2+i1, 16 rows / 1024 thr / 2 bands per block (grid 1280).
// finalize: standalone 1-block (fused variant hit cross-XCD fence cost, R21).
constexpr int L      = 160000;
constexpr int BATCH  = 8;
constexpr int NB     = 8;
constexpr int NHOPS  = 156;
constexpr int NCHUNK = 155;
constexpr int RS     = 289;   // swizzled row stride (fi)
constexpr float TWO_PI = 6.28318530717958647692f;
constexpr float INVL = 1.0f / (float)L;

__device__ __forceinline__ float2 cmulf(float2 a, float2 b) {
  return make_float2(a.x * b.x - a.y * b.y, a.x * b.y + a.y * b.x);
}

__device__ __forceinline__ float2 cisf(float a) {
  float s, c;
  __sincosf(a, &s, &c);
  return make_float2(c, s);
}

__device__ __forceinline__ float2 conjf(float2 a) { return make_float2(a.x, -a.y); }

__device__ __forceinline__ int pad8(int i) { return i + (i >> 3); }

template <int SIGN>
__device__ __forceinline__ void bf4s(float2* v) {
  float2 t0 = make_float2(v[0].x + v[2].x, v[0].y + v[2].y);
  float2 t1 = make_float2(v[0].x - v[2].x, v[0].y - v[2].y);
  float2 t2 = make_float2(v[1].x + v[3].x, v[1].y + v[3].y);
  float2 t3 = make_float2(v[1].x - v[3].x, v[1].y - v[3].y);
  v[0] = make_float2(t0.x + t2.x, t0.y + t2.y);
  v[2] = make_float2(t0.x - t2.x, t0.y - t2.y);
  if constexpr (SIGN < 0) {
    v[1] = make_float2(t1.x + t3.y, t1.y - t3.x);
    v[3] = make_float2(t1.x - t3.y, t1.y + t3.x);
  } else {
    v[1] = make_float2(t1.x - t3.y, t1.y + t3.x);
    v[3] = make_float2(t1.x + t3.y, t1.y - t3.x);
  }
}

template <int SIGN>
__device__ __forceinline__ void bf5s(float2* v) {
  const float c1 = 0.30901699437494745f, s1 = 0.9510565162951535f;
  const float c2 = -0.8090169943749475f, s2 = 0.5877852522924731f;
  float2 t1 = make_float2(v[1].x + v[4].x, v[1].y + v[4].y);
  float2 t3 = make_float2(v[1].x - v[4].x, v[1].y - v[4].y);
  float2 t2 = make_float2(v[2].x + v[3].x, v[2].y + v[3].y);
  float2 t4 = make_float2(v[2].x - v[3].x, v[2].y - v[3].y);
  float2 a = make_float2(v[0].x + c1 * t1.x + c2 * t2.x, v[0].y + c1 * t1.y + c2 * t2.y);
  float2 b = make_float2(s1 * t3.x + s2 * t4.x, s1 * t3.y + s2 * t4.y);
  float2 c = make_float2(v[0].x + c2 * t1.x + c1 * t2.x, v[0].y + c2 * t1.y + c1 * t2.y);
  float2 d = make_float2(s2 * t3.x - s1 * t4.x, s2 * t3.y - s1 * t4.y);
  v[0] = make_float2(v[0].x + t1.x + t2.x, v[0].y + t1.y + t2.y);
  if constexpr (SIGN < 0) {
    v[1] = make_float2(a.x + b.y, a.y - b.x);
    v[4] = make_float2(a.x - b.y, a.y + b.x);
    v[2] = make_float2(c.x + d.y, c.y - d.x);
    v[3] = make_float2(c.x - d.y, c.y + d.x);
  } else {
    v[1] = make_float2(a.x - b.y, a.y + b.x);
    v[4] = make_float2(a.x + b.y, a.y - b.x);
    v[2] = make_float2(c.x - d.y, c.y + d.x);
    v[3] = make_float2(c.x + d.y, c.y - d.x);
  }
}

template <int R>
__device__ __forceinline__ void twchain(float2* v, float2 t1) {
  float2 t = t1;
  v[1] = cmulf(v[1], t);
#pragma unroll
  for (int r = 2; r < R; ++r) { t = cmulf(t, t1); v[r] = cmulf(v[r], t); }
}

__device__ __forceinline__ int rev3_5(int q) {
  int q5 = q / 5, q25 = q / 25;
  int d0 = q - 5 * q5, d1 = q5 - 5 * q25;
  return 25 * d0 + 5 * d1 + q25;
}

__device__ __forceinline__ int rev3_4(int q) {
  return ((q & 3) << 4) | (q & 12) | (q >> 4);
}

// ---------- single-butterfly DIF-625 stage (128 lanes/column, f1) ----------
template <int SUB, int SIGN>
__device__ __forceinline__ void dif5_stage_1b(float2* a, int idx) {
  int j = idx % SUB;
  int b = (idx / SUB) * (5 * SUB) + j;
  float2 u[5];
#pragma unroll
  for (int r = 0; r < 5; ++r) u[r] = a[b + SUB * r];
  bf5s<SIGN>(u);
  twchain<5>(u, cisf((float)SIGN * (TWO_PI / (float)(5 * SUB)) * (float)j));
#pragma unroll
  for (int r = 0; r < 5; ++r) a[b + SUB * r] = u[r];
}

// ---------- dual-butterfly DIF-625 stage, precomputed twiddles (i2) ----------
template <int SUB>
__device__ __forceinline__ void dif5_ip_stage_t(float2* a, int ln, float2 t1a, float2 t1b) {
  int i1 = ln, i2 = ln + 64;
  bool g2 = (i2 < 125);
  int j1 = i1 % SUB, j2 = i2 % SUB;
  int b1 = (i1 / SUB) * (5 * SUB) + j1;
  int b2 = (i2 / SUB) * (5 * SUB) + j2;
  float2 u[5], v[5];
#pragma unroll
  for (int r = 0; r < 5; ++r) u[r] = a[b1 + SUB * r];
  if (g2) {
#pragma unroll
    for (int r = 0; r < 5; ++r) v[r] = a[b2 + SUB * r];
  }
  bf5s<1>(u);
  twchain<5>(u, t1a);
  if (g2) {
    bf5s<1>(v);
    twchain<5>(v, t1b);
  }
#pragma unroll
  for (int r = 0; r < 5; ++r) a[b1 + SUB * r] = u[r];
  if (g2) {
#pragma unroll
    for (int r = 0; r < 5; ++r) a[b2 + SUB * r] = v[r];
  }
}

// ---------- in-place DIF-256, pad8-swizzled, hoisted twiddles (fi) ----------
template <int SIGN>
__device__ __forceinline__ void dif256sw_tw(float2* a, int ln,
                                            float2 tw1, float2 tw2, float2 tw3) {
  {
    int b = pad8(ln);            // + 72*r exact
    float2 u[4];
#pragma unroll
    for (int r = 0; r < 4; ++r) u[r] = a[b + 72 * r];
    bf4s<SIGN>(u);
    twchain<4>(u, tw1);
#pragma unroll
    for (int r = 0; r < 4; ++r) a[b + 72 * r] = u[r];
  }
  {
    int j = ln & 15, b = pad8(64 * (ln >> 4) + j);   // + 18*r exact
    float2 u[4];
#pragma unroll
    for (int r = 0; r < 4; ++r) u[r] = a[b + 18 * r];
    bf4s<SIGN>(u);
    twchain<4>(u, tw2);
#pragma unroll
    for (int r = 0; r < 4; ++r) a[b + 18 * r] = u[r];
  }
  {
    int j = ln & 3, jb = 16 * (ln >> 2) + j;
    float2 u[4];
#pragma unroll
    for (int r = 0; r < 4; ++r) u[r] = a[pad8(jb + 4 * r)];
    bf4s<SIGN>(u);
    twchain<4>(u, tw3);
#pragma unroll
    for (int r = 0; r < 4; ++r) a[pad8(jb + 4 * r)] = u[r];
  }
  {
    float2 u[4];
#pragma unroll
    for (int r = 0; r < 4; ++r) u[r] = a[pad8(4 * ln + r)];
    bf4s<SIGN>(u);
    int rv = rev3_4(ln);
#pragma unroll
    for (int r = 0; r < 4; ++r) a[pad8(64 * r + rv)] = u[r];
  }
}

// ---------- F1: float4 pack, 2 waves per 625-column, chained epilogue; zero E ----------
__global__ __launch_bounds__(512) void f1_kernel(const float* __restrict__ win,
                                                 const float* __restrict__ oin,
                                                 float2* __restrict__ G,
                                                 float* __restrict__ E) {
  __shared__ float2 A[4 * 625];    // 20 KB
  int blk = blockIdx.x;            // grid = BATCH * 64 = 512
  int tid = threadIdx.x;
  int gid = blk * 512 + tid;
  if (gid < 2 * BATCH * NB * NHOPS) E[gid] = 0.0f;   // replaces memset launch
  int sig = blk >> 6, g = blk & 63;
  int n1base = g * 4;
  const float4* wp4 = (const float4*)(win + (size_t)sig * L);
  const float4* op4 = (const float4*)(oin + (size_t)sig * L);
  for (int r = tid; r < 625; r += 512) {
    float4 wv = wp4[r * 64 + g];
    float4 ov = op4[r * 64 + g];
    A[0 * 625 + r] = make_float2(wv.x, ov.x);
    A[1 * 625 + r] = make_float2(wv.y, ov.y);
    A[2 * 625 + r] = make_float2(wv.z, ov.z);
    A[3 * 625 + r] = make_float2(wv.w, ov.w);
  }
  __syncthreads();
  // 2 waves per column: 128 lanes, 1 butterfly each (125 active)
  int col = tid >> 7, idx = tid & 127;
  float2* a = A + col * 625;
  bool act = (idx < 125);
  if (act) dif5_stage_1b<125, -1>(a, idx);
  __syncthreads();
  if (act) dif5_stage_1b<25, -1>(a, idx);
  __syncthreads();
  if (act) dif5_stage_1b<5, -1>(a, idx);
  __syncthreads();
  if (act) {
    float2 u[5];
#pragma unroll
    for (int r = 0; r < 5; ++r) u[r] = a[5 * idx + r];
    bf5s<-1>(u);
    int rv = rev3_5(idx);
#pragma unroll
    for (int r = 0; r < 5; ++r) a[125 * r + rv] = u[r];
  }
  __syncthreads();
  // chained epilogue over 512 threads: cc fixed, k2 steps by 128
  int cc = tid & 3, k20 = tid >> 2;   // k20 in [0,128)
  int n1 = n1base + cc;
  float w = -(TWO_PI / (float)L) * (float)n1;
  float2 t = cisf(w * (float)k20);
  float2 stp = cisf(w * 128.0f);
  for (int k2 = k20; k2 < 625; k2 += 128) {
    G[(size_t)sig * L + k2 * 256 + n1] = cmulf(A[cc * 625 + k2], t);
    t = cmulf(t, stp);
  }
}

// ---------- FI: fused f2+i1, 16 rows / 1024 thr / 2 bands per block (grid 1280). ----------
__global__ __launch_bounds__(1024) void fi_kernel(const float2* __restrict__ G,
                                                  __half2* __restrict__ H) {
  __shared__ float2 Xb[16 * RS];   // forward spectra (pad8)
  __shared__ float2 Wb[16 * RS];   // inverse work (stages 1-3)
  int blk = blockIdx.x;            // grid = 4 * BATCH * 40 = 1280
  int bg  = blk / (BATCH * 40);    // band-group 0..3 (2 bands each)
  int rem = blk - bg * (BATCH * 40);
  int sig = rem / 40, gr = rem % 40;
  int k2base = gr * 16;
  int tid = threadIdx.x;
  int wv = tid >> 6, ln = tid & 63;
  int k2 = k2base + wv;
  bool act = (k2 < 625);
  float2* xr = Xb + wv * RS;
  float2* wr = Wb + wv * RS;

  // ---- hoisted stage twiddles (inverse sign; forward uses conj) ----
  float2 tw1 = cisf((TWO_PI / 256.0f) * (float)ln);
  float2 tw2 = cisf((TWO_PI / 64.0f) * (float)(ln & 15));
  float2 tw3 = cisf((TWO_PI / 16.0f) * (float)(ln & 3));

  // ---- forward DIF-256 of own row (once per band-group) ----
  if (act) {
#pragma unroll
    for (int r = 0; r < 4; ++r)
      xr[pad8(ln + 64 * r)] = G[(size_t)sig * L + k2 * 256 + ln + 64 * r];
    dif256sw_tw<-1>(xr, ln, conjf(tw1), conjf(tw2), conjf(tw3));
  }

  // ---- hoisted per-lane LDS bases (stage strides are exact in pad8 space) ----
  int b1 = pad8(ln);                              // + 72*r
  int b2 = pad8(64 * (ln >> 4) + (ln & 15));      // + 18*r
  int jb3 = 16 * (ln >> 2) + (ln & 3);            // pad8(jb3 + 4*r)
  int kb = 625 * ln + k2;                         // + 40000*r  (bin number)

  // ---- fused stage-4 + epilogue constants ----
  int cc = tid & 15, q = tid >> 4;                // q in 0..63 (butterfly id)
  int rq = rev3_4(q);                             // n1 = 64*r + rq
  int k2e = k2base + cc;
  bool eact = (k2e < 625);
  float a0 = (TWO_PI / (float)L) * (float)k2e;
  float2 t0q = cisf(a0 * (float)rq);
  float2 stp = cisf(a0 * 64.0f);

#pragma unroll
  for (int bi = 0; bi < 2; ++bi) {
    int band = bg * 2 + bi;
    unsigned lo1, d1, lo2, d2;
    if (band < 7) {
      lo1 = 10000u * band + 1u;              d1 = 9999u;
      lo2 = (unsigned)L - 10000u * (band + 1); d2 = 9999u;
    } else {
      lo1 = 70001u; d1 = 19998u;             // 70001..89999
      lo2 = 0u;     d2 = 0u;                 // DC bin -> band 7
    }
    if (act) {
      float2 u[4];
      // stage 1: read Xb with in-register band mask, write Wb
#pragma unroll
      for (int r = 0; r < 4; ++r) {
        float2 x = xr[b1 + 72 * r];
        unsigned k = (unsigned)(kb + 40000 * r);
        bool in = ((k - lo1) <= d1) || ((k - lo2) <= d2);
        u[r] = in ? x : make_float2(0.0f, 0.0f);
      }
      bf4s<1>(u);
      twchain<4>(u, tw1);
#pragma unroll
      for (int r = 0; r < 4; ++r) wr[b1 + 72 * r] = u[r];
      // stage 2
#pragma unroll
      for (int r = 0; r < 4; ++r) u[r] = wr[b2 + 18 * r];
      bf4s<1>(u);
      twchain<4>(u, tw2);
#pragma unroll
      for (int r = 0; r < 4; ++r) wr[b2 + 18 * r] = u[r];
      // stage 3
#pragma unroll
      for (int r = 0; r < 4; ++r) u[r] = wr[pad8(jb3 + 4 * r)];
      bf4s<1>(u);
      twchain<4>(u, tw3);
#pragma unroll
      for (int r = 0; r < 4; ++r) wr[pad8(jb3 + 4 * r)] = u[r];
    }
    __syncthreads();
    // fused stage 4 + epilogue: butterfly q of row cc, outputs n1 = 64r + rq
    if (eact) {
      size_t obase = (size_t)(sig * NB + band) * L;
      int b4 = cc * RS + pad8(4 * q);             // + r exact (r<4)
      float2 v[4];
#pragma unroll
      for (int r = 0; r < 4; ++r) v[r] = Wb[b4 + r];
      bf4s<1>(v);
      float2 t = t0q;
#pragma unroll
      for (int r = 0; r < 4; ++r) {
        int n1 = 64 * r + rq;
        float2 val = cmulf(v[r], t);
        H[obase + (size_t)n1 * 625 + k2e] = __floats2half2_rn(val.x * INVL, val.y * INVL);
        t = cmulf(t, stp);
      }
    }
    __syncthreads();
  }
}

// ---------- I2: ONE column per wave, 4 columns / 256-thr block, grid 4096.
//              LDS exactly 20000 B -> 8 blocks/CU = 32 waves/CU, 2 exact
//              rounds. Energy in registers, partials spilled into dead A. ----------
__global__ __launch_bounds__(256, 8) void i2_kernel(const __half2* __restrict__ H,
                                                    float* __restrict__ E) {
  __shared__ float2 A[4 * 625];       // 20000 B (one column per wave)
  int blk = blockIdx.x;               // grid = BATCH*NB*64 = 4096
  int g = blk & 63, sb = blk >> 6;
  int band = sb & 7, sig = sb >> 3;
  int tid = threadIdx.x;
  int wv = tid >> 6, ln = tid & 63;
  size_t base = (size_t)(sig * NB + band) * L;
  int n1 = 4 * g + wv;                // covers 0..255 across 64 blocks x 4 waves
  const __half2* Hc = H + base + (size_t)n1 * 625;
  int j1 = ln, j2 = ln + 64;
  bool g2 = (j2 < 125);
  __half2 h1[5], h2[5];
#pragma unroll
  for (int r = 0; r < 5; ++r) h1[r] = Hc[j1 + 125 * r];
  if (g2) {
#pragma unroll
    for (int r = 0; r < 5; ++r) h2[r] = Hc[j2 + 125 * r];
  }
  float2 tS1a = cisf((TWO_PI / 625.0f) * (float)j1);
  float2 tS1b = cisf((TWO_PI / 625.0f) * (float)j2);
  float2 tS2a = cisf((TWO_PI / 125.0f) * (float)(j1 % 25));
  float2 tS2b = cisf((TWO_PI / 125.0f) * (float)(j2 % 25));
  float2 tS3a = cisf((TWO_PI / 25.0f) * (float)(j1 % 5));
  float2 tS3b = cisf((TWO_PI / 25.0f) * (float)(j2 % 5));
  float2* a = A + wv * 625;

  // ---- stage 1 (from registers) ----
  {
    float2 u[5];
#pragma unroll
    for (int r = 0; r < 5; ++r) u[r] = __half22float2(h1[r]);
    bf5s<1>(u);
    twchain<5>(u, tS1a);
#pragma unroll
    for (int r = 0; r < 5; ++r) a[j1 + 125 * r] = u[r];
    if (g2) {
      float2 v[5];
#pragma unroll
      for (int r = 0; r < 5; ++r) v[r] = __half22float2(h2[r]);
      bf5s<1>(v);
      twchain<5>(v, tS1b);
#pragma unroll
      for (int r = 0; r < 5; ++r) a[j2 + 125 * r] = v[r];
    }
  }
  // ---- stages 2-3 ----
  dif5_ip_stage_t<25>(a, ln, tS2a, tS2b);
  dif5_ip_stage_t<5>(a, ln, tS3a, tS3b);
  // ---- final stage ----
  {
    float2 u[5], v[5];
#pragma unroll
    for (int r = 0; r < 5; ++r) u[r] = a[5 * j1 + r];
    if (g2) {
#pragma unroll
      for (int r = 0; r < 5; ++r) v[r] = a[5 * j2 + r];
    }
    bf5s<1>(u);
    if (g2) bf5s<1>(v);
    int rv1 = rev3_5(j1), rv2 = rev3_5(j2);
#pragma unroll
    for (int r = 0; r < 5; ++r) a[125 * r + rv1] = u[r];
    if (g2) {
#pragma unroll
      for (int r = 0; r < 5; ++r) a[125 * r + rv2] = v[r];
    }
  }
  // ---- energy pass into registers ----
  float ex[3] = {0.0f, 0.0f, 0.0f}, ey[3] = {0.0f, 0.0f, 0.0f};
#pragma unroll
  for (int k = 0; k < 3; ++k) {
    int h = ln + 64 * k;
    if (h < NHOPS) {
#pragma unroll
      for (int d = 0; d < 4; ++d) {
        float2 z = a[4 * h + d];
        ex[k] += z.x * z.x;
        ey[k] += z.y * z.y;
      }
    }
  }
  __syncthreads();                       // all waves done with A
  float* Ps = (float*)A;                 // 4 waves x 312 floats = 4992 B scratch
#pragma unroll
  for (int k = 0; k < 3; ++k) {
    int h = ln + 64 * k;
    if (h < NHOPS) {
      Ps[wv * (2 * NHOPS) + h] = ex[k];
      Ps[wv * (2 * NHOPS) + NHOPS + h] = ey[k];
    }
  }
  __syncthreads();
  int eb = (sig * NB + band) * NHOPS;
  for (int idx = tid; idx < 2 * NHOPS; idx += 256) {
    float v = Ps[idx] + Ps[2 * NHOPS + idx] + Ps[4 * NHOPS + idx] + Ps[6 * NHOPS + idx];
    int comp = idx / NHOPS, h = idx - comp * NHOPS;
    atomicAdd(&E[comp * (BATCH * NB * NHOPS) + eb + h], v);
  }
}

// ---------- finalize: loudness, diff, softmax (H pre-scaled by 1/L -> SC = 1/2048) ----------
__global__ __launch_bounds__(1024) void finalize_kernel(const float* __restrict__ E,
                                                        float* __restrict__ out) {
  constexpr int ND = BATCH * NB * NCHUNK;  // 9920
  constexpr float SC = 1.0f / 2048.0f;
  __shared__ float diffs[ND];
  __shared__ float sred[1024];
  int tid = threadIdx.x;
  for (int idx = tid; idx < ND; idx += 1024) {
    int sb = idx / NCHUNK;
    int k = idx - sb * NCHUNK;
    float msw = (E[sb * NHOPS + k] + E[sb * NHOPS + k + 1]) * SC;
    float mso = (E[64 * NHOPS + sb * NHOPS + k] + E[64 * NHOPS + sb * NHOPS + k + 1]) * SC;
    float lw = -0.691f + 10.0f * log10f(msw + 1e-12f);
    float lo = -0.691f + 10.0f * log10f(mso + 1e-12f);
    diffs[idx] = lw - lo;
  }
  __syncthreads();
  float mx = -3.4e38f;
  for (int idx = tid; idx < ND; idx += 1024) mx = fmaxf(mx, diffs[idx]);
  sred[tid] = mx;
  __syncthreads();
  for (int s = 512; s > 0; s >>= 1) {
    if (tid < s) sred[tid] = fmaxf(sred[tid], sred[tid + s]);
    __syncthreads();
  }
  float gmax = sred[0];
  __syncthreads();
  float se = 0.0f, swd = 0.0f;
  for (int idx = tid; idx < ND; idx += 1024) {
    float d = diffs[idx];
    float e = expf(d - gmax);
    se += e;
    swd += d * e;
  }
  sred[tid] = se; __syncthreads();
  for (int s = 512; s > 0; s >>= 1) { if (tid < s) sred[tid] += sred[tid + s]; __syncthreads(); }
  float tot = sred[0];
  __syncthreads();
  sred[tid] = swd; __syncthreads();
  for (int s = 512; s > 0; s >>= 1) { if (tid < s) sred[tid] += sred[tid + s]; __syncthreads(); }
  if (tid == 0) out[0] = sred[0] / tot;
}

extern "C" void kernel_launch(void* const* d_in, const int* in_sizes, int n_in,
                              void* d_out, int out_size, void* d_ws, size_t ws_size,
                              hipStream_t stream) {
  (void)in_sizes; (void)n_in; (void)out_size; (void)ws_size;
  char* ws = (char*)d_ws;
  float2*  G = (float2*)ws;                        // 10,240,000 B
  __half2* H = (__half2*)(ws + 10240000);          // 40,960,000 B (fp16)
  float*   E = (float*)(ws + 51200000);            // 79,872 B [2][64][156]
  const float* w = (const float*)d_in[0];
  const float* o = (const float*)d_in[1];

  f1_kernel<<<dim3(BATCH * 64), dim3(512), 0, stream>>>(w, o, G, E);
  fi_kernel<<<dim3(4 * BATCH * 40), dim3(1024), 0, stream>>>(G, H);
  i2_kernel<<<dim3(BATCH * NB * 64), dim3(256), 0, stream>>>(H, E);
  finalize_kernel<<<dim3(1), dim3(1024), 0, stream>>>(E, (float*)d_out);
}